// Round 2
// baseline (3562.596 us; speedup 1.0000x reference)
//
#include <hip/hip_runtime.h>
#include <hip/hip_bf16.h>

using bf16 = __hip_bfloat16;
using s16x4 = __attribute__((ext_vector_type(4))) short;
using s16x8 = __attribute__((ext_vector_type(8))) short;
using f32x4 = __attribute__((ext_vector_type(4))) float;

#define DI __device__ __forceinline__

DI float ldf(const float* p) { return *p; }
DI float ldf(const bf16* p) { return __bfloat162float(*p); }
DI void stf(float* p, float v) { *p = v; }
DI void stf(bf16* p, float v) { *p = __float2bfloat16(v); }

DI float gelu_f(float x) { return 0.5f * x * (1.f + erff(x * 0.7071067811865475f)); }

// ---------------- diagnostic: encode ws_size into output ----------------
__global__ void diag_k(float* out, float v) { out[0] = v; }

// ---------------- fp32 -> bf16 weight conversion ----------------
__global__ void f2bf_k(const float* __restrict__ in, bf16* __restrict__ out, int n) {
    int i = blockIdx.x * 256 + threadIdx.x;
    if (i < n) out[i] = __float2bfloat16(in[i]);
}

// ---------------- depthwise 3x3 conv (SAME, zero pad), optional residual ----
// pixel n = y*32+x within a 32x32 image, channels contiguous, row stride rs,
// input channel offset coff. out[pix*ors + c] = (RESID? in_center:0) + bias[c] + conv
template <typename TI, typename TO, bool RESID>
__global__ __launch_bounds__(256) void dwconv_k(
    const TI* __restrict__ in, long rs, long coff,
    const float* __restrict__ w, const float* __restrict__ bias,
    TO* __restrict__ out, long ors, int Cn)
{
    const int pix = blockIdx.x;
    const int b = pix >> 10, y = (pix >> 5) & 31, xx = pix & 31;
    const long brow = (long)b << 10;
    for (int c = threadIdx.x; c < Cn; c += 256) {
        float acc = bias[c];
#pragma unroll
        for (int dy = -1; dy <= 1; dy++) {
            const int yy = y + dy;
            if ((unsigned)yy > 31u) continue;
#pragma unroll
            for (int dx = -1; dx <= 1; dx++) {
                const int xv = xx + dx;
                if ((unsigned)xv > 31u) continue;
                acc += ldf(in + (brow + yy * 32 + xv) * rs + coff + c) *
                       w[c * 9 + (dy + 1) * 3 + (dx + 1)];
            }
        }
        if (RESID) acc += ldf(in + (long)pix * rs + coff + c);
        stf(out + (long)pix * ors + c, acc);
    }
}

// ---------------- LayerNorm over C=512, fp32 in -> bf16 out ----------------
__global__ __launch_bounds__(64) void ln_k(const float* __restrict__ x,
                                           const float* __restrict__ w,
                                           const float* __restrict__ bp,
                                           bf16* __restrict__ out)
{
    const size_t row = blockIdx.x;
    const float* xr = x + row * 512;
    const int t = threadIdx.x;
    alignas(16) float v[8];
    *(float4*)&v[0] = *(const float4*)(xr + t * 8);
    *(float4*)&v[4] = *(const float4*)(xr + t * 8 + 4);
    float s = 0.f;
#pragma unroll
    for (int j = 0; j < 8; j++) s += v[j];
#pragma unroll
    for (int mm = 32; mm; mm >>= 1) s += __shfl_xor(s, mm);
    const float mu = s * (1.f / 512.f);
    float q = 0.f;
#pragma unroll
    for (int j = 0; j < 8; j++) { v[j] -= mu; q += v[j] * v[j]; }
#pragma unroll
    for (int mm = 32; mm; mm >>= 1) q += __shfl_xor(q, mm);
    const float rstd = rsqrtf(q * (1.f / 512.f) + 1e-6f);
    alignas(16) float wv[8], bv[8];
    *(float4*)&wv[0] = *(const float4*)(w + t * 8);
    *(float4*)&wv[4] = *(const float4*)(w + t * 8 + 4);
    *(float4*)&bv[0] = *(const float4*)(bp + t * 8);
    *(float4*)&bv[4] = *(const float4*)(bp + t * 8 + 4);
    alignas(16) bf16 o[8];
#pragma unroll
    for (int j = 0; j < 8; j++) o[j] = __float2bfloat16(v[j] * rstd * wv[j] + bv[j]);
    *(uint4*)(out + row * 512 + t * 8) = *(const uint4*)o;
}

// ---------------- bf16 MFMA GEMM: C[M,N] = A[M,K] * Bw[N,K]^T ----------------
// EPI 0: store bf16. EPI 1: +bias, gelu -> bf16. EPI 2: +bias +resid -> fp32 (in-place ok).
template <int EPI>
__global__ __launch_bounds__(256) void gemm_k(
    const bf16* __restrict__ A, const bf16* __restrict__ Bw,
    const float* __restrict__ bias, const float* resid,
    bf16* __restrict__ outb, float* outf,
    int M, int Nn, int K)
{
    __shared__ __align__(16) short As[128 * 40];
    __shared__ __align__(16) short Bs[128 * 40];
    const int t = threadIdx.x;
    const int m0 = blockIdx.x * 128;
    const int n0 = blockIdx.y * 128;
    const int lane = t & 63;
    const int wv = t >> 6;
    const int wr = wv >> 1, wc = wv & 1;
    const int lr = lane & 15, lg = lane >> 4;

    f32x4 acc[4][4] = {};

    const int ar0 = t >> 2, ak0 = (t & 3) * 8;   // rows 0..63
    const int ar1 = ar0 + 64;                    // rows 64..127

    for (int k0 = 0; k0 < K; k0 += 32) {
        const uint4 a0 = *(const uint4*)(A + (size_t)(m0 + ar0) * K + k0 + ak0);
        const uint4 a1 = *(const uint4*)(A + (size_t)(m0 + ar1) * K + k0 + ak0);
        const uint4 b0 = *(const uint4*)(Bw + (size_t)(n0 + ar0) * K + k0 + ak0);
        const uint4 b1 = *(const uint4*)(Bw + (size_t)(n0 + ar1) * K + k0 + ak0);
        __syncthreads();
        *(uint4*)(As + ar0 * 40 + ak0) = a0;
        *(uint4*)(As + ar1 * 40 + ak0) = a1;
        *(uint4*)(Bs + ar0 * 40 + ak0) = b0;
        *(uint4*)(Bs + ar1 * 40 + ak0) = b1;
        __syncthreads();
        s16x8 aF[4], bF[4];
#pragma unroll
        for (int i = 0; i < 4; i++)
            aF[i] = *(const s16x8*)(As + (wr * 64 + i * 16 + lr) * 40 + lg * 8);
#pragma unroll
        for (int j = 0; j < 4; j++)
            bF[j] = *(const s16x8*)(Bs + (wc * 64 + j * 16 + lr) * 40 + lg * 8);
#pragma unroll
        for (int i = 0; i < 4; i++)
#pragma unroll
            for (int j = 0; j < 4; j++)
                acc[i][j] = __builtin_amdgcn_mfma_f32_16x16x32_bf16(aF[i], bF[j], acc[i][j], 0, 0, 0);
    }

#pragma unroll
    for (int i = 0; i < 4; i++) {
#pragma unroll
        for (int j = 0; j < 4; j++) {
#pragma unroll
            for (int r = 0; r < 4; r++) {
                const int row = m0 + wr * 64 + i * 16 + lg * 4 + r;
                const int col = n0 + wc * 64 + j * 16 + lr;
                float v = acc[i][j][r];
                if (EPI > 0) v += bias[col];
                const size_t idx = (size_t)row * Nn + col;
                if (EPI == 0) outb[idx] = __float2bfloat16(v);
                else if (EPI == 1) outb[idx] = __float2bfloat16(gelu_f(v));
                else outf[idx] = v + resid[idx];
            }
        }
    }
}

// ---------------- column softmax stats over tokens (N=1024) ----------------
// grid: Bc*8 blocks of 64 threads. b local to chunk.
__global__ __launch_bounds__(64) void ksoft_stats_k(const bf16* __restrict__ qkv,
                                                    float* __restrict__ cmax,
                                                    float* __restrict__ csum)
{
    const int b = blockIdx.x >> 3;
    const int c = (blockIdx.x & 7) * 64 + threadIdx.x;
    const bf16* kp = qkv + (size_t)b * 1024 * 1536 + 512 + c;
    float m = -3.0e38f, s = 0.f;
    for (int n = 0; n < 1024; n++) {
        const float kv = __bfloat162float(kp[(size_t)n * 1536]);
        if (kv > m) { s = s * expf(m - kv) + 1.f; m = kv; }
        else s += expf(kv - m);
    }
    cmax[b * 512 + c] = m;
    csum[b * 512 + c] = s;
}

// ---------------- ktv[b,h,k,v] = scale/sum_k * sum_n softmax(k)*v -----------
__global__ __launch_bounds__(256) void ktv_k(const bf16* __restrict__ qkv,
                                             const float* __restrict__ cmax,
                                             const float* __restrict__ csum,
                                             float* __restrict__ ktv)
{
    const int b = blockIdx.x >> 3, hh = blockIdx.x & 7;
    const bf16* kb = qkv + (size_t)b * 1024 * 1536 + 512 + hh * 64;
    const bf16* vb = kb + 512;
    __shared__ __align__(16) bf16 Ks[16 * 64];
    __shared__ __align__(16) bf16 Vs[16 * 64];
    const int t = threadIdx.x;
    const int kk = t & 63, vg = t >> 6;
    const float mk = cmax[b * 512 + hh * 64 + kk];
    float acc[16] = {};
    const int sr = t >> 4, sc = (t & 15) * 4;
    for (int n0 = 0; n0 < 1024; n0 += 16) {
        __syncthreads();
        *(s16x4*)(void*)(Ks + sr * 64 + sc) = *(const s16x4*)(const void*)(kb + (size_t)(n0 + sr) * 1536 + sc);
        *(s16x4*)(void*)(Vs + sr * 64 + sc) = *(const s16x4*)(const void*)(vb + (size_t)(n0 + sr) * 1536 + sc);
        __syncthreads();
#pragma unroll
        for (int i = 0; i < 16; i++) {
            const float p = expf(__bfloat162float(Ks[i * 64 + kk]) - mk);
#pragma unroll
            for (int j = 0; j < 16; j++)
                acc[j] += p * __bfloat162float(Vs[i * 64 + vg * 16 + j]);
        }
    }
    const float inv = 0.125f / csum[b * 512 + hh * 64 + kk];  // scale = d^-0.5 folded
    float* o = ktv + ((size_t)(b * 8 + hh) * 64 + kk) * 64 + vg * 16;
#pragma unroll
    for (int j = 0; j < 16; j++) o[j] = acc[j] * inv;
}

// ---------------- xs += q @ ktv_scaled + q * vconv  (in place) --------------
// grid: Bc*8*32 blocks of 256.
__global__ __launch_bounds__(256) void attnout_k(
    float* xs, const bf16* __restrict__ qkv,
    const float* __restrict__ ktv, const bf16* __restrict__ vc)
{
    const int nc = blockIdx.x & 31, hh = (blockIdx.x >> 5) & 7, b = blockIdx.x >> 8;
    __shared__ __align__(16) float kt[64 * 64];
    __shared__ __align__(16) bf16 qs[32 * 64];
    const int t = threadIdx.x;
    const float4* ksrc = (const float4*)(ktv + (size_t)(b * 8 + hh) * 4096);
    for (int u = t; u < 1024; u += 256) ((float4*)kt)[u] = ksrc[u];
    const int n0 = nc * 32;
    {
        const int r = t >> 3, cc = (t & 7) * 8;
        *(uint4*)(qs + r * 64 + cc) =
            *(const uint4*)(qkv + ((size_t)b * 1024 + n0 + r) * 1536 + hh * 64 + cc);
    }
    __syncthreads();
    const int dv = t & 63, rb = (t >> 6) * 8;
    for (int r = rb; r < rb + 8; r++) {
        float fa = 0.f;
#pragma unroll
        for (int kk = 0; kk < 64; kk++)
            fa += __bfloat162float(qs[r * 64 + kk]) * kt[kk * 64 + dv];
        const size_t idx = ((size_t)b * 1024 + n0 + r) * 512 + hh * 64 + dv;
        const float qv = __bfloat162float(qs[r * 64 + dv]);
        xs[idx] = xs[idx] + fa + qv * __bfloat162float(vc[idx]);
    }
}

// ---------------- workspace layout (bytes) ----------------------------------
// Chunked: Bc=8 images per chunk, 4 chunks. Residual spine lives in d_out (fp32).
static constexpr int    BC       = 8;
static constexpr int    NCHUNK   = 4;
static constexpr size_t OFF_WQ   = 0;          // bf16 1536x512   = 1.5MB
static constexpr size_t OFF_W1   = 1572864;    // bf16 2048x512   = 2MB
static constexpr size_t OFF_W2   = 3670016;    // bf16 512x2048   = 2MB
static constexpr size_t OFF_CUR  = 5767168;    // bf16 (8,1024,512)  = 8MB
static constexpr size_t OFF_QKV  = 14155776;   // bf16 (8,1024,1536) = 24MB
static constexpr size_t OFF_CMAX = 39321600;   // fp32 (8,512)
static constexpr size_t OFF_CSUM = 39337984;
static constexpr size_t OFF_KTV  = 39354368;   // fp32 (8,8,64,64) = 1MB
static constexpr size_t OFF_VC   = 40402944;   // bf16 (8,1024,512)  = 8MB
static constexpr size_t OFF_HG   = 14155776;   // bf16 (8,1024,2048) = 32MB (over dead qkv/stats/vc)
static constexpr size_t OFF_H2   = 47710208;   // bf16 (8,1024,2048) = 32MB
static constexpr size_t WS_NEED  = 81264640;   // ~77.5MB

extern "C" void kernel_launch(void* const* d_in, const int* in_sizes, int n_in,
                              void* d_out, int out_size, void* d_ws, size_t ws_size,
                              hipStream_t stream)
{
    const float* x     = (const float*)d_in[0];
    const float* cpe_w = (const float*)d_in[1];
    const float* cpe_b = (const float*)d_in[2];
    const float* ln1_w = (const float*)d_in[3];
    const float* ln1_b = (const float*)d_in[4];
    const float* qkv_w = (const float*)d_in[5];
    const float* crpe_w= (const float*)d_in[6];
    const float* crpe_b= (const float*)d_in[7];
    const float* ln2_w = (const float*)d_in[8];
    const float* ln2_b = (const float*)d_in[9];
    const float* fc1_w = (const float*)d_in[10];
    const float* fc1_b = (const float*)d_in[11];
    const float* dw_w  = (const float*)d_in[12];
    const float* dw_b  = (const float*)d_in[13];
    const float* fc2_w = (const float*)d_in[14];
    const float* fc2_b = (const float*)d_in[15];
    float* spine = (float*)d_out;   // fp32 residual spine lives in d_out
    char* ws = (char*)d_ws;

    if (ws_size < WS_NEED) {  // diagnostic: surface ws_size in the output
        diag_k<<<1, 1, 0, stream>>>(spine, (float)ws_size);
        return;
    }

    bf16*  wq   = (bf16*)(ws + OFF_WQ);
    bf16*  w1   = (bf16*)(ws + OFF_W1);
    bf16*  w2   = (bf16*)(ws + OFF_W2);
    bf16*  cur  = (bf16*)(ws + OFF_CUR);
    bf16*  qkv  = (bf16*)(ws + OFF_QKV);
    float* cmax = (float*)(ws + OFF_CMAX);
    float* csum = (float*)(ws + OFF_CSUM);
    float* ktv  = (float*)(ws + OFF_KTV);
    bf16*  vc   = (bf16*)(ws + OFF_VC);
    bf16*  hg   = (bf16*)(ws + OFF_HG);
    bf16*  h2   = (bf16*)(ws + OFF_H2);

    // weights -> bf16
    f2bf_k<<<(1536 * 512 + 255) / 256, 256, 0, stream>>>(qkv_w, wq, 1536 * 512);
    f2bf_k<<<(2048 * 512 + 255) / 256, 256, 0, stream>>>(fc1_w, w1, 2048 * 512);
    f2bf_k<<<(2048 * 512 + 255) / 256, 256, 0, stream>>>(fc2_w, w2, 2048 * 512);

    // CPE (full batch): spine = x + dwconv(x) + cpe_b
    dwconv_k<float, float, true><<<32768, 256, 0, stream>>>(x, 512, 0, cpe_w, cpe_b, spine, 512, 512);

    const int Mc = BC * 1024;  // 8192 rows per chunk
    for (int c = 0; c < NCHUNK; c++) {
        float* xs = spine + (size_t)c * Mc * 512;
        // LN1
        ln_k<<<Mc, 64, 0, stream>>>(xs, ln1_w, ln1_b, cur);
        // qkv = cur @ qkv_w^T
        gemm_k<0><<<dim3(Mc / 128, 12), 256, 0, stream>>>(cur, wq, nullptr, nullptr, qkv, nullptr, Mc, 1536, 512);
        // column-softmax stats for k
        ksoft_stats_k<<<BC * 8, 64, 0, stream>>>(qkv, cmax, csum);
        // ktv (scale & 1/sum folded)
        ktv_k<<<BC * 8, 256, 0, stream>>>(qkv, cmax, csum, ktv);
        // crpe conv on v
        dwconv_k<bf16, bf16, false><<<Mc, 256, 0, stream>>>(qkv, 1536, 1024, crpe_w, crpe_b, vc, 512, 512);
        // xs += q@ktv + q*vconv (in place)
        attnout_k<<<BC * 8 * 32, 256, 0, stream>>>(xs, qkv, ktv, vc);
        // LN2
        ln_k<<<Mc, 64, 0, stream>>>(xs, ln2_w, ln2_b, cur);
        // fc1 + gelu
        gemm_k<1><<<dim3(Mc / 128, 16), 256, 0, stream>>>(cur, w1, fc1_b, nullptr, hg, nullptr, Mc, 2048, 512);
        // hidden dwconv residual: h2 = hg + dwconv(hg) + dw_b
        dwconv_k<bf16, bf16, true><<<Mc, 256, 0, stream>>>(hg, 2048, 0, dw_w, dw_b, h2, 2048, 2048);
        // xs += h2 @ fc2_w^T + fc2_b (in place via resid==outf)
        gemm_k<2><<<dim3(Mc / 128, 4), 256, 0, stream>>>(h2, w2, fc2_b, xs, nullptr, xs, Mc, 512, 2048);
    }
}

// Round 3
// 1233.458 us; speedup vs baseline: 2.8883x; 2.8883x over previous
//
#include <hip/hip_runtime.h>
#include <hip/hip_bf16.h>

using bf16 = __hip_bfloat16;
using s16x4 = __attribute__((ext_vector_type(4))) short;
using s16x8 = __attribute__((ext_vector_type(8))) short;
using f32x4 = __attribute__((ext_vector_type(4))) float;

#define DI __device__ __forceinline__

DI float b2f(short s) { union { unsigned u; float f; } z; z.u = ((unsigned)(unsigned short)s) << 16; return z.f; }
DI short f2b(float f) { bf16 t = __float2bfloat16(f); return *(short*)&t; }

DI float gelu_f(float x) { return 0.5f * x * (1.f + erff(x * 0.7071067811865475f)); }

// load 8 contiguous values as float
DI void ld8(const bf16* p, float* f) {
    s16x8 x = *(const s16x8*)(const void*)p;
#pragma unroll
    for (int c = 0; c < 8; c++) f[c] = b2f(x[c]);
}
DI void ld8(const float* p, float* f) {
    float4 a = *(const float4*)p, b = *(const float4*)(p + 4);
    f[0]=a.x; f[1]=a.y; f[2]=a.z; f[3]=a.w; f[4]=b.x; f[5]=b.y; f[6]=b.z; f[7]=b.w;
}
DI void st8(bf16* p, const float* f) {
    s16x8 o;
#pragma unroll
    for (int c = 0; c < 8; c++) o[c] = f2b(f[c]);
    *(s16x8*)(void*)p = o;
}
DI void st8(float* p, const float* f) {
    *(float4*)p = make_float4(f[0], f[1], f[2], f[3]);
    *(float4*)(p + 4) = make_float4(f[4], f[5], f[6], f[7]);
}

// ---------------- diagnostic: encode ws_size into output ----------------
__global__ void diag_k(float* out, float v) { out[0] = v; }

// ---------------- fp32 -> bf16 weight conversion ----------------
__global__ void f2bf_k(const float* __restrict__ in, bf16* __restrict__ out, int n) {
    int i = blockIdx.x * 256 + threadIdx.x;
    if (i < n) out[i] = __float2bfloat16(in[i]);
}

// ---------------- depthwise 3x3 conv, LDS-staged, 8 ch/block ----------------
// block = (image b, channel-group g of 8). Stages 32x32x8 tile in LDS.
// out[pix*ors + g*8+c] = (RESID? in:0) + bias + conv.  gshift = log2(Cn/8).
template <typename TI, typename TO, bool RESID>
__global__ __launch_bounds__(256) void dwconv2_k(
    const TI* in, long rs, long coff,
    const float* __restrict__ w, const float* __restrict__ bias,
    TO* out, long ors, int gshift)
{
    __shared__ __align__(16) TI tile[1024 * 8];
    const int t = threadIdx.x;
    const int b = blockIdx.x >> gshift;
    const int g = blockIdx.x & ((1 << gshift) - 1);
    const TI* src = in + ((long)b << 10) * rs + coff + g * 8;
#pragma unroll
    for (int u = 0; u < 4; u++) {
        const int px = t + u * 256;
        if constexpr (sizeof(TI) == 2) {
            *(s16x8*)(void*)(tile + px * 8) = *(const s16x8*)(const void*)(src + (long)px * rs);
        } else {
            *(float4*)(tile + px * 8) = *(const float4*)(src + (long)px * rs);
            *(float4*)(tile + px * 8 + 4) = *(const float4*)(src + (long)px * rs + 4);
        }
    }
    float wr[9][8], br[8];
#pragma unroll
    for (int c = 0; c < 8; c++) {
#pragma unroll
        for (int j = 0; j < 9; j++) wr[j][c] = w[(g * 8 + c) * 9 + j];
        br[c] = bias[g * 8 + c];
    }
    __syncthreads();
    const int xx = t & 31;
    const int y0 = (t >> 5) << 2;
#pragma unroll
    for (int yi = 0; yi < 4; yi++) {
        const int y = y0 + yi;
        float acc[8];
#pragma unroll
        for (int c = 0; c < 8; c++) acc[c] = br[c];
#pragma unroll
        for (int dy = -1; dy <= 1; dy++) {
            const int yy = y + dy;
            if ((unsigned)yy > 31u) continue;
#pragma unroll
            for (int dx = -1; dx <= 1; dx++) {
                const int xv = xx + dx;
                if ((unsigned)xv > 31u) continue;
                float f[8];
                ld8(tile + (yy * 32 + xv) * 8, f);
                const int j = (dy + 1) * 3 + (dx + 1);
#pragma unroll
                for (int c = 0; c < 8; c++) acc[c] += f[c] * wr[j][c];
            }
        }
        if (RESID) {
            float f[8];
            ld8(tile + (y * 32 + xx) * 8, f);
#pragma unroll
            for (int c = 0; c < 8; c++) acc[c] += f[c];
        }
        st8(out + ((long)(b * 1024 + y * 32 + xx)) * ors + g * 8, acc);
    }
}

// ---------------- LayerNorm over C=512, fp32 in -> bf16 out ----------------
__global__ __launch_bounds__(64) void ln_k(const float* __restrict__ x,
                                           const float* __restrict__ w,
                                           const float* __restrict__ bp,
                                           bf16* __restrict__ out)
{
    const size_t row = blockIdx.x;
    const float* xr = x + row * 512;
    const int t = threadIdx.x;
    alignas(16) float v[8];
    *(float4*)&v[0] = *(const float4*)(xr + t * 8);
    *(float4*)&v[4] = *(const float4*)(xr + t * 8 + 4);
    float s = 0.f;
#pragma unroll
    for (int j = 0; j < 8; j++) s += v[j];
#pragma unroll
    for (int mm = 32; mm; mm >>= 1) s += __shfl_xor(s, mm);
    const float mu = s * (1.f / 512.f);
    float q = 0.f;
#pragma unroll
    for (int j = 0; j < 8; j++) { v[j] -= mu; q += v[j] * v[j]; }
#pragma unroll
    for (int mm = 32; mm; mm >>= 1) q += __shfl_xor(q, mm);
    const float rstd = rsqrtf(q * (1.f / 512.f) + 1e-6f);
    alignas(16) float wv[8], bv[8];
    *(float4*)&wv[0] = *(const float4*)(w + t * 8);
    *(float4*)&wv[4] = *(const float4*)(w + t * 8 + 4);
    *(float4*)&bv[0] = *(const float4*)(bp + t * 8);
    *(float4*)&bv[4] = *(const float4*)(bp + t * 8 + 4);
    alignas(16) bf16 o[8];
#pragma unroll
    for (int j = 0; j < 8; j++) o[j] = __float2bfloat16(v[j] * rstd * wv[j] + bv[j]);
    *(uint4*)(out + row * 512 + t * 8) = *(const uint4*)o;
}

// ---------------- bf16 MFMA GEMM: C[M,N] = A[M,K] * Bw[N,K]^T ----------------
// EPI 0: store bf16. EPI 1: +bias, gelu -> bf16. EPI 2: +bias +resid -> fp32 (in-place ok).
template <int EPI>
__global__ __launch_bounds__(256) void gemm_k(
    const bf16* __restrict__ A, const bf16* __restrict__ Bw,
    const float* __restrict__ bias, const float* resid,
    bf16* __restrict__ outb, float* outf,
    int M, int Nn, int K)
{
    __shared__ __align__(16) short As[128 * 40];
    __shared__ __align__(16) short Bs[128 * 40];
    const int t = threadIdx.x;
    const int m0 = blockIdx.x * 128;
    const int n0 = blockIdx.y * 128;
    const int lane = t & 63;
    const int wv = t >> 6;
    const int wr = wv >> 1, wc = wv & 1;
    const int lr = lane & 15, lg = lane >> 4;

    f32x4 acc[4][4] = {};

    const int ar0 = t >> 2, ak0 = (t & 3) * 8;
    const int ar1 = ar0 + 64;

    for (int k0 = 0; k0 < K; k0 += 32) {
        const uint4 a0 = *(const uint4*)(A + (size_t)(m0 + ar0) * K + k0 + ak0);
        const uint4 a1 = *(const uint4*)(A + (size_t)(m0 + ar1) * K + k0 + ak0);
        const uint4 b0 = *(const uint4*)(Bw + (size_t)(n0 + ar0) * K + k0 + ak0);
        const uint4 b1 = *(const uint4*)(Bw + (size_t)(n0 + ar1) * K + k0 + ak0);
        __syncthreads();
        *(uint4*)(As + ar0 * 40 + ak0) = a0;
        *(uint4*)(As + ar1 * 40 + ak0) = a1;
        *(uint4*)(Bs + ar0 * 40 + ak0) = b0;
        *(uint4*)(Bs + ar1 * 40 + ak0) = b1;
        __syncthreads();
        s16x8 aF[4], bF[4];
#pragma unroll
        for (int i = 0; i < 4; i++)
            aF[i] = *(const s16x8*)(As + (wr * 64 + i * 16 + lr) * 40 + lg * 8);
#pragma unroll
        for (int j = 0; j < 4; j++)
            bF[j] = *(const s16x8*)(Bs + (wc * 64 + j * 16 + lr) * 40 + lg * 8);
#pragma unroll
        for (int i = 0; i < 4; i++)
#pragma unroll
            for (int j = 0; j < 4; j++)
                acc[i][j] = __builtin_amdgcn_mfma_f32_16x16x32_bf16(aF[i], bF[j], acc[i][j], 0, 0, 0);
    }

#pragma unroll
    for (int i = 0; i < 4; i++) {
#pragma unroll
        for (int j = 0; j < 4; j++) {
#pragma unroll
            for (int r = 0; r < 4; r++) {
                const int row = m0 + wr * 64 + i * 16 + lg * 4 + r;
                const int col = n0 + wc * 64 + j * 16 + lr;
                float v = acc[i][j][r];
                if (EPI > 0) v += bias[col];
                const size_t idx = (size_t)row * Nn + col;
                if (EPI == 0) outb[idx] = __float2bfloat16(v);
                else if (EPI == 1) outb[idx] = __float2bfloat16(gelu_f(v));
                else outf[idx] = v + resid[idx];
            }
        }
    }
}

// ---------------- ktv partials: no max-subtraction softmax -------------------
// ktv'[b,h,k,v] = sum_n exp(k[n])*v[n,v], csum[b,h,k] = sum_n exp(k[n])
// grid: Bc*8*4 blocks (4-way token split), 256 threads.
__global__ __launch_bounds__(256) void ktv_part_k(const bf16* __restrict__ qkv,
                                                  float* __restrict__ ktvp,
                                                  float* __restrict__ csp)
{
    const int b = blockIdx.x >> 5;
    const int hh = (blockIdx.x >> 2) & 7;
    const int sp = blockIdx.x & 3;
    const bf16* kb = qkv + (size_t)b * 1024 * 1536 + 512 + hh * 64;
    const bf16* vb = kb + 512;
    __shared__ __align__(16) bf16 Ks[16 * 64];
    __shared__ __align__(16) bf16 Vs[16 * 64];
    const int t = threadIdx.x;
    const int kk = t & 63, vg = t >> 6;
    float acc[16] = {};
    float psum = 0.f;
    const int sr = t >> 4, sc = (t & 15) * 4;
    for (int n0 = sp * 256; n0 < sp * 256 + 256; n0 += 16) {
        __syncthreads();
        *(s16x4*)(void*)(Ks + sr * 64 + sc) = *(const s16x4*)(const void*)(kb + (size_t)(n0 + sr) * 1536 + sc);
        *(s16x4*)(void*)(Vs + sr * 64 + sc) = *(const s16x4*)(const void*)(vb + (size_t)(n0 + sr) * 1536 + sc);
        __syncthreads();
#pragma unroll
        for (int i = 0; i < 16; i++) {
            const float p = __expf(b2f(*(const short*)(const void*)(Ks + i * 64 + kk)));
            psum += p;
            float vv[16];
            ld8(Vs + i * 64 + vg * 16, vv);
            ld8(Vs + i * 64 + vg * 16 + 8, vv + 8);
#pragma unroll
            for (int j = 0; j < 16; j++) acc[j] += p * vv[j];
        }
    }
    const int bh4 = (b * 8 + hh) * 4 + sp;
    float* o = ktvp + (size_t)bh4 * 4096 + kk * 64 + vg * 16;
#pragma unroll
    for (int j = 0; j < 16; j++) o[j] = acc[j];
    if (vg == 0) csp[bh4 * 64 + kk] = psum;
}

// ---------------- ktv reduce: fold 4 partials, scale by 0.125/csum ----------
// grid: Bc*8 blocks, 256 threads; 16 entries/thread.
__global__ __launch_bounds__(256) void ktv_red_k(const float* __restrict__ ktvp,
                                                 const float* __restrict__ csp,
                                                 float* __restrict__ ktv)
{
    const int bh = blockIdx.x;
    const int t = threadIdx.x;
#pragma unroll
    for (int i = 0; i < 16; i++) {
        const int e = t + 256 * i;
        const int kk = e >> 6;
        float cs = 0.f, v = 0.f;
#pragma unroll
        for (int sp = 0; sp < 4; sp++) {
            cs += csp[(bh * 4 + sp) * 64 + kk];
            v += ktvp[(size_t)(bh * 4 + sp) * 4096 + e];
        }
        ktv[(size_t)bh * 4096 + e] = v * (0.125f / cs);
    }
}

// ---------------- xs += q @ ktv_scaled + q * vconv  (in place) --------------
// grid: Bc*8*32 blocks of 256.
__global__ __launch_bounds__(256) void attnout_k(
    float* xs, const bf16* __restrict__ qkv,
    const float* __restrict__ ktv, const bf16* __restrict__ vc)
{
    const int nc = blockIdx.x & 31, hh = (blockIdx.x >> 5) & 7, b = blockIdx.x >> 8;
    __shared__ __align__(16) float kt[64 * 64];
    __shared__ __align__(16) bf16 qs[32 * 64];
    const int t = threadIdx.x;
    const float4* ksrc = (const float4*)(ktv + (size_t)(b * 8 + hh) * 4096);
    for (int u = t; u < 1024; u += 256) ((float4*)kt)[u] = ksrc[u];
    const int n0 = nc * 32;
    {
        const int r = t >> 3, cc = (t & 7) * 8;
        *(uint4*)(qs + r * 64 + cc) =
            *(const uint4*)(qkv + ((size_t)b * 1024 + n0 + r) * 1536 + hh * 64 + cc);
    }
    __syncthreads();
    const int dv = t & 63, rb = (t >> 6) * 8;
    for (int r = rb; r < rb + 8; r++) {
        float fa = 0.f;
#pragma unroll
        for (int kk = 0; kk < 64; kk++)
            fa += b2f(*(const short*)(const void*)(qs + r * 64 + kk)) * kt[kk * 64 + dv];
        const size_t idx = ((size_t)b * 1024 + n0 + r) * 512 + hh * 64 + dv;
        const float qv = b2f(*(const short*)(const void*)(qs + r * 64 + dv));
        xs[idx] = xs[idx] + fa + qv * __bfloat162float(vc[idx]);
    }
}

// ---------------- workspace layout (bytes) ----------------------------------
// Chunked: Bc=8 images per chunk, 4 chunks. Residual spine lives in d_out (fp32).
static constexpr int    BC       = 8;
static constexpr int    NCHUNK   = 4;
static constexpr size_t OFF_WQ   = 0;          // bf16 1536x512   = 1.5MB
static constexpr size_t OFF_W1   = 1572864;    // bf16 2048x512   = 2MB
static constexpr size_t OFF_W2   = 3670016;    // bf16 512x2048   = 2MB
static constexpr size_t OFF_CUR  = 5767168;    // bf16 (8,1024,512)  = 8MB
static constexpr size_t OFF_QKV  = 14155776;   // bf16 (8,1024,1536) = 24MB
static constexpr size_t OFF_KTVP = 39321600;   // fp32 (64,4,4096) = 4MB
static constexpr size_t OFF_CSP  = 43515904;   // fp32 (64,4,64)   = 64KB
static constexpr size_t OFF_KTV  = 43581440;   // fp32 (64,4096)   = 1MB
static constexpr size_t OFF_VC   = 44630016;   // bf16 (8,1024,512)  = 8MB
static constexpr size_t OFF_HG   = 14155776;   // bf16 (8,1024,2048) = 32MB (over dead qkv..vc head)
static constexpr size_t OFF_H2   = 47710208;   // bf16 (8,1024,2048) = 32MB (over dead vc tail)
static constexpr size_t WS_NEED  = 81264640;   // ~77.5MB

extern "C" void kernel_launch(void* const* d_in, const int* in_sizes, int n_in,
                              void* d_out, int out_size, void* d_ws, size_t ws_size,
                              hipStream_t stream)
{
    const float* x     = (const float*)d_in[0];
    const float* cpe_w = (const float*)d_in[1];
    const float* cpe_b = (const float*)d_in[2];
    const float* ln1_w = (const float*)d_in[3];
    const float* ln1_b = (const float*)d_in[4];
    const float* qkv_w = (const float*)d_in[5];
    const float* crpe_w= (const float*)d_in[6];
    const float* crpe_b= (const float*)d_in[7];
    const float* ln2_w = (const float*)d_in[8];
    const float* ln2_b = (const float*)d_in[9];
    const float* fc1_w = (const float*)d_in[10];
    const float* fc1_b = (const float*)d_in[11];
    const float* dw_w  = (const float*)d_in[12];
    const float* dw_b  = (const float*)d_in[13];
    const float* fc2_w = (const float*)d_in[14];
    const float* fc2_b = (const float*)d_in[15];
    float* spine = (float*)d_out;   // fp32 residual spine lives in d_out
    char* ws = (char*)d_ws;

    if (ws_size < WS_NEED) {  // diagnostic: surface ws_size in the output
        diag_k<<<1, 1, 0, stream>>>(spine, (float)ws_size);
        return;
    }

    bf16*  wq   = (bf16*)(ws + OFF_WQ);
    bf16*  w1   = (bf16*)(ws + OFF_W1);
    bf16*  w2   = (bf16*)(ws + OFF_W2);
    bf16*  cur  = (bf16*)(ws + OFF_CUR);
    bf16*  qkv  = (bf16*)(ws + OFF_QKV);
    float* ktvp = (float*)(ws + OFF_KTVP);
    float* csp  = (float*)(ws + OFF_CSP);
    float* ktv  = (float*)(ws + OFF_KTV);
    bf16*  vc   = (bf16*)(ws + OFF_VC);
    bf16*  hg   = (bf16*)(ws + OFF_HG);
    bf16*  h2   = (bf16*)(ws + OFF_H2);

    // weights -> bf16
    f2bf_k<<<(1536 * 512 + 255) / 256, 256, 0, stream>>>(qkv_w, wq, 1536 * 512);
    f2bf_k<<<(2048 * 512 + 255) / 256, 256, 0, stream>>>(fc1_w, w1, 2048 * 512);
    f2bf_k<<<(2048 * 512 + 255) / 256, 256, 0, stream>>>(fc2_w, w2, 2048 * 512);

    // CPE (full batch): spine = x + dwconv(x) + cpe_b   (32 imgs x 64 groups)
    dwconv2_k<float, float, true><<<32 * 64, 256, 0, stream>>>(x, 512, 0, cpe_w, cpe_b, spine, 512, 6);

    const int Mc = BC * 1024;  // 8192 rows per chunk
    for (int c = 0; c < NCHUNK; c++) {
        float* xs = spine + (size_t)c * Mc * 512;
        // LN1
        ln_k<<<Mc, 64, 0, stream>>>(xs, ln1_w, ln1_b, cur);
        // qkv = cur @ qkv_w^T
        gemm_k<0><<<dim3(Mc / 128, 12), 256, 0, stream>>>(cur, wq, nullptr, nullptr, qkv, nullptr, Mc, 1536, 512);
        // ktv partials (exp-sum fused, no separate stats pass)
        ktv_part_k<<<BC * 8 * 4, 256, 0, stream>>>(qkv, ktvp, csp);
        ktv_red_k<<<BC * 8, 256, 0, stream>>>(ktvp, csp, ktv);
        // crpe conv on v (8 imgs x 64 groups)
        dwconv2_k<bf16, bf16, false><<<BC * 64, 256, 0, stream>>>(qkv, 1536, 1024, crpe_w, crpe_b, vc, 512, 6);
        // xs += q@ktv + q*vconv (in place)
        attnout_k<<<BC * 8 * 32, 256, 0, stream>>>(xs, qkv, ktv, vc);
        // LN2
        ln_k<<<Mc, 64, 0, stream>>>(xs, ln2_w, ln2_b, cur);
        // fc1 + gelu
        gemm_k<1><<<dim3(Mc / 128, 16), 256, 0, stream>>>(cur, w1, fc1_b, nullptr, hg, nullptr, Mc, 2048, 512);
        // hidden dwconv residual: h2 = hg + dwconv(hg) + dw_b (8 imgs x 256 groups)
        dwconv2_k<bf16, bf16, true><<<BC * 256, 256, 0, stream>>>(hg, 2048, 0, dw_w, dw_b, h2, 2048, 8);
        // xs += h2 @ fc2_w^T + fc2_b (in place via resid==outf)
        gemm_k<2><<<dim3(Mc / 128, 4), 256, 0, stream>>>(h2, w2, fc2_b, xs, nullptr, xs, Mc, 512, 2048);
    }
}

// Round 4
// 952.461 us; speedup vs baseline: 3.7404x; 1.2950x over previous
//
#include <hip/hip_runtime.h>
#include <hip/hip_bf16.h>

using bf16 = __hip_bfloat16;
using s16x4 = __attribute__((ext_vector_type(4))) short;
using s16x8 = __attribute__((ext_vector_type(8))) short;
using f32x4 = __attribute__((ext_vector_type(4))) float;

#define DI __device__ __forceinline__

DI float b2f(short s) { union { unsigned u; float f; } z; z.u = ((unsigned)(unsigned short)s) << 16; return z.f; }

DI float gelu_f(float x) { return 0.5f * x * (1.f + erff(x * 0.7071067811865475f)); }

DI void stf(float* p, float v) { *p = v; }
DI void stf(bf16* p, float v) { *p = __float2bfloat16(v); }

// load 8 contiguous values as float
DI void ld8(const bf16* p, float* f) {
    s16x8 x = *(const s16x8*)(const void*)p;
#pragma unroll
    for (int c = 0; c < 8; c++) f[c] = b2f(x[c]);
}
DI void ld8(const float* p, float* f) {
    float4 a = *(const float4*)p, b = *(const float4*)(p + 4);
    f[0]=a.x; f[1]=a.y; f[2]=a.z; f[3]=a.w; f[4]=b.x; f[5]=b.y; f[6]=b.z; f[7]=b.w;
}

// async global->LDS, 16B per lane; LDS dest = wave-uniform base + lane*16
typedef const __attribute__((address_space(1))) void* gp_t;
typedef __attribute__((address_space(3))) void* lp_t;
DI void gload_lds16(const void* g, void* l) {
    __builtin_amdgcn_global_load_lds((gp_t)g, (lp_t)l, 16, 0, 0);
}

// ---------------- diagnostic: encode ws_size into output ----------------
__global__ void diag_k(float* out, float v) { out[0] = v; }

// ---------------- fp32 -> bf16 weight conversion ----------------
__global__ void f2bf_k(const float* __restrict__ in, bf16* __restrict__ out, int n) {
    int i = blockIdx.x * 256 + threadIdx.x;
    if (i < n) out[i] = __float2bfloat16(in[i]);
}

// ---------------- depthwise 3x3 conv v3: coalesced rolling-row --------------
// block = (img, cg of 64 channels, band of 8 rows). grid = nimg * ncg * 4.
// Staging: row of 32px x 64ch read coalesced (thread = px, ch-octet), stored
// channel-major in LDS [64][34]. Compute: wave = x-octet, lane = channel;
// rolling 3-row x 10-px register window; coalesced channel-contiguous stores.
DI void tap10(const float* r, float w0, float w1, float w2, float* acc) {
#pragma unroll
    for (int i = 0; i < 8; i++)
        acc[i] += w0 * r[i] + w1 * r[i + 1] + w2 * r[i + 2];
}

template <typename TI, typename TO, bool RESID>
__global__ __launch_bounds__(256) void conv3_k(
    const TI* in, long rs, long coff,
    const float* __restrict__ w, const float* __restrict__ bias,
    TO* out, long ors, int gshift)
{
    __shared__ float buf[2][64][34];
    const int t = threadIdx.x;
    const int band = blockIdx.x & 3;
    const int cg = (blockIdx.x >> 2) & ((1 << gshift) - 1);
    const int img = blockIdx.x >> (2 + gshift);
    const int y0 = band * 8;

    // staging role
    const int spx = t >> 3;          // pixel 0..31
    const int sce = (t & 7) * 8;     // channel elem 0..56
    const TI* gsrc = in + ((long)img << 10) * rs + coff + (long)cg * 64 + sce;

    // compute role
    const int c = t & 63;            // channel within group
    const int xg = t >> 6;           // x-octet 0..3
    const int xb = xg * 8;

    // per-lane weights
    const int gch = (cg << 6) + c;
    float wv9[9];
#pragma unroll
    for (int j = 0; j < 9; j++) wv9[j] = w[gch * 9 + j];
    const float bw = bias[gch];

    auto stage = [&](int row) {
        float f[8];
        ld8(gsrc + (long)(row * 32 + spx) * rs, f);
        float* d = &buf[row & 1][0][0];
#pragma unroll
        for (int k = 0; k < 8; k++) d[(sce + k) * 34 + spx] = f[k];
    };
    auto slice = [&](int row, float* r) {
        const float* s = &buf[row & 1][c][0];
        r[0] = (xb == 0) ? 0.f : s[xb - 1];
#pragma unroll
        for (int i = 0; i < 4; i++) {
            float2 v = *(const float2*)(s + xb + 2 * i);
            r[1 + 2 * i] = v.x; r[2 + 2 * i] = v.y;
        }
        r[9] = (xb + 8 >= 32) ? 0.f : s[xb + 8];
    };

    float r0[10], r1[10], r2[10];
    if (y0 > 0) stage(y0 - 1);
    __syncthreads();
    if (y0 > 0) slice(y0 - 1, r0);
    else {
#pragma unroll
        for (int i = 0; i < 10; i++) r0[i] = 0.f;
    }
    stage(y0);
    __syncthreads();
    slice(y0, r1);

    for (int y = y0; y < y0 + 8; ++y) {
        const int yn = y + 1;
        if (yn <= 31) stage(yn);
        __syncthreads();
        if (yn <= 31) slice(yn, r2);
        else {
#pragma unroll
            for (int i = 0; i < 10; i++) r2[i] = 0.f;
        }
        float acc[8];
#pragma unroll
        for (int i = 0; i < 8; i++) acc[i] = bw;
        tap10(r0, wv9[0], wv9[1], wv9[2], acc);
        tap10(r1, wv9[3], wv9[4], wv9[5], acc);
        tap10(r2, wv9[6], wv9[7], wv9[8], acc);
        if (RESID) {
#pragma unroll
            for (int i = 0; i < 8; i++) acc[i] += r1[i + 1];
        }
        TO* o = out + ((long)(img * 1024 + y * 32 + xb)) * ors + (cg << 6) + c;
#pragma unroll
        for (int i = 0; i < 8; i++) stf(o + (long)i * ors, acc[i]);
#pragma unroll
        for (int i = 0; i < 10; i++) { r0[i] = r1[i]; r1[i] = r2[i]; }
    }
}

// ---------------- LayerNorm over C=512, fp32 in -> bf16 out ----------------
__global__ __launch_bounds__(64) void ln_k(const float* __restrict__ x,
                                           const float* __restrict__ w,
                                           const float* __restrict__ bp,
                                           bf16* __restrict__ out)
{
    const size_t row = blockIdx.x;
    const float* xr = x + row * 512;
    const int t = threadIdx.x;
    alignas(16) float v[8];
    *(float4*)&v[0] = *(const float4*)(xr + t * 8);
    *(float4*)&v[4] = *(const float4*)(xr + t * 8 + 4);
    float s = 0.f;
#pragma unroll
    for (int j = 0; j < 8; j++) s += v[j];
#pragma unroll
    for (int mm = 32; mm; mm >>= 1) s += __shfl_xor(s, mm);
    const float mu = s * (1.f / 512.f);
    float q = 0.f;
#pragma unroll
    for (int j = 0; j < 8; j++) { v[j] -= mu; q += v[j] * v[j]; }
#pragma unroll
    for (int mm = 32; mm; mm >>= 1) q += __shfl_xor(q, mm);
    const float rstd = rsqrtf(q * (1.f / 512.f) + 1e-6f);
    alignas(16) float wv[8], bv[8];
    *(float4*)&wv[0] = *(const float4*)(w + t * 8);
    *(float4*)&wv[4] = *(const float4*)(w + t * 8 + 4);
    *(float4*)&bv[0] = *(const float4*)(bp + t * 8);
    *(float4*)&bv[4] = *(const float4*)(bp + t * 8 + 4);
    alignas(16) bf16 o[8];
#pragma unroll
    for (int j = 0; j < 8; j++) o[j] = __float2bfloat16(v[j] * rstd * wv[j] + bv[j]);
    *(uint4*)(out + row * 512 + t * 8) = *(const uint4*)o;
}

// ---------------- bf16 MFMA GEMM: C[M,N] = A[M,K] * Bw[N,K]^T ----------------
// global_load_lds staging (m97 2-barrier structure), LDS linear [128][32].
// EPI 0: store bf16. EPI 1: +bias, gelu -> bf16. EPI 2: +bias +resid -> fp32.
template <int EPI>
__global__ __launch_bounds__(256) void gemm_k(
    const bf16* __restrict__ A, const bf16* __restrict__ Bw,
    const float* __restrict__ bias, const float* resid,
    bf16* __restrict__ outb, float* outf,
    int M, int Nn, int K)
{
    __shared__ __align__(16) short As[128 * 32];
    __shared__ __align__(16) short Bs[128 * 32];
    const int t = threadIdx.x;
    const int m0 = blockIdx.x * 128;
    const int n0 = blockIdx.y * 128;
    const int lane = t & 63;
    const int wv = t >> 6;
    const int wr = wv >> 1, wc = wv & 1;
    const int lr = lane & 15, lg = lane >> 4;

    f32x4 acc[4][4] = {};

    // staging map: wave wv covers LDS bytes [wv*2048, wv*2048+2048) per tile,
    // lane l writes 16B at base + l*16 -> row = wv*32 + i*16 + (l>>2), k = (l&3)*8
    const int srow = wv * 32 + (lane >> 2);
    const int ske  = (lane & 3) * 8;
    const bf16* Ag0 = A  + (size_t)(m0 + srow) * K + ske;
    const bf16* Ag1 = A  + (size_t)(m0 + srow + 16) * K + ske;
    const bf16* Bg0 = Bw + (size_t)(n0 + srow) * K + ske;
    const bf16* Bg1 = Bw + (size_t)(n0 + srow + 16) * K + ske;
    char* Al0 = (char*)As + wv * 2048;
    char* Al1 = Al0 + 1024;
    char* Bl0 = (char*)Bs + wv * 2048;
    char* Bl1 = Bl0 + 1024;

    for (int k0 = 0; k0 < K; k0 += 32) {
        __syncthreads();                 // prev iter's ds_reads complete
        gload_lds16(Ag0 + k0, Al0);
        gload_lds16(Ag1 + k0, Al1);
        gload_lds16(Bg0 + k0, Bl0);
        gload_lds16(Bg1 + k0, Bl1);
        __syncthreads();                 // vmcnt(0) drain + barrier
        s16x8 aF[4], bF[4];
#pragma unroll
        for (int i = 0; i < 4; i++)
            aF[i] = *(const s16x8*)(As + (wr * 64 + i * 16 + lr) * 32 + lg * 8);
#pragma unroll
        for (int j = 0; j < 4; j++)
            bF[j] = *(const s16x8*)(Bs + (wc * 64 + j * 16 + lr) * 32 + lg * 8);
#pragma unroll
        for (int i = 0; i < 4; i++)
#pragma unroll
            for (int j = 0; j < 4; j++)
                acc[i][j] = __builtin_amdgcn_mfma_f32_16x16x32_bf16(aF[i], bF[j], acc[i][j], 0, 0, 0);
    }

#pragma unroll
    for (int i = 0; i < 4; i++) {
#pragma unroll
        for (int j = 0; j < 4; j++) {
#pragma unroll
            for (int r = 0; r < 4; r++) {
                const int row = m0 + wr * 64 + i * 16 + lg * 4 + r;
                const int col = n0 + wc * 64 + j * 16 + lr;
                float v = acc[i][j][r];
                if (EPI > 0) v += bias[col];
                const size_t idx = (size_t)row * Nn + col;
                if (EPI == 0) outb[idx] = __float2bfloat16(v);
                else if (EPI == 1) outb[idx] = __float2bfloat16(gelu_f(v));
                else outf[idx] = v + resid[idx];
            }
        }
    }
}

// ---------------- ktv partials: no max-subtraction softmax -------------------
__global__ __launch_bounds__(256) void ktv_part_k(const bf16* __restrict__ qkv,
                                                  float* __restrict__ ktvp,
                                                  float* __restrict__ csp)
{
    const int b = blockIdx.x >> 5;
    const int hh = (blockIdx.x >> 2) & 7;
    const int sp = blockIdx.x & 3;
    const bf16* kb = qkv + (size_t)b * 1024 * 1536 + 512 + hh * 64;
    const bf16* vb = kb + 512;
    __shared__ __align__(16) bf16 Ks[16 * 64];
    __shared__ __align__(16) bf16 Vs[16 * 64];
    const int t = threadIdx.x;
    const int kk = t & 63, vg = t >> 6;
    float acc[16] = {};
    float psum = 0.f;
    const int sr = t >> 4, sc = (t & 15) * 4;
    for (int n0 = sp * 256; n0 < sp * 256 + 256; n0 += 16) {
        __syncthreads();
        *(s16x4*)(void*)(Ks + sr * 64 + sc) = *(const s16x4*)(const void*)(kb + (size_t)(n0 + sr) * 1536 + sc);
        *(s16x4*)(void*)(Vs + sr * 64 + sc) = *(const s16x4*)(const void*)(vb + (size_t)(n0 + sr) * 1536 + sc);
        __syncthreads();
#pragma unroll
        for (int i = 0; i < 16; i++) {
            const float p = __expf(b2f(*(const short*)(const void*)(Ks + i * 64 + kk)));
            psum += p;
            float vv[16];
            ld8(Vs + i * 64 + vg * 16, vv);
            ld8(Vs + i * 64 + vg * 16 + 8, vv + 8);
#pragma unroll
            for (int j = 0; j < 16; j++) acc[j] += p * vv[j];
        }
    }
    const int bh4 = (b * 8 + hh) * 4 + sp;
    float* o = ktvp + (size_t)bh4 * 4096 + kk * 64 + vg * 16;
#pragma unroll
    for (int j = 0; j < 16; j++) o[j] = acc[j];
    if (vg == 0) csp[bh4 * 64 + kk] = psum;
}

// ---------------- ktv reduce: fold 4 partials, scale by 0.125/csum ----------
__global__ __launch_bounds__(256) void ktv_red_k(const float* __restrict__ ktvp,
                                                 const float* __restrict__ csp,
                                                 float* __restrict__ ktv)
{
    const int bh = blockIdx.x;
    const int t = threadIdx.x;
#pragma unroll
    for (int i = 0; i < 16; i++) {
        const int e = t + 256 * i;
        const int kk = e >> 6;
        float cs = 0.f, v = 0.f;
#pragma unroll
        for (int sp = 0; sp < 4; sp++) {
            cs += csp[(bh * 4 + sp) * 64 + kk];
            v += ktvp[(size_t)(bh * 4 + sp) * 4096 + e];
        }
        ktv[(size_t)bh * 4096 + e] = v * (0.125f / cs);
    }
}

// ---------------- xs += q @ ktv_scaled + q * vconv  (in place) --------------
__global__ __launch_bounds__(256) void attnout_k(
    float* xs, const bf16* __restrict__ qkv,
    const float* __restrict__ ktv, const bf16* __restrict__ vc)
{
    const int nc = blockIdx.x & 31, hh = (blockIdx.x >> 5) & 7, b = blockIdx.x >> 8;
    __shared__ __align__(16) float kt[64 * 64];
    __shared__ __align__(16) bf16 qs[32 * 64];
    const int t = threadIdx.x;
    const float4* ksrc = (const float4*)(ktv + (size_t)(b * 8 + hh) * 4096);
    for (int u = t; u < 1024; u += 256) ((float4*)kt)[u] = ksrc[u];
    const int n0 = nc * 32;
    {
        const int r = t >> 3, cc = (t & 7) * 8;
        *(uint4*)(qs + r * 64 + cc) =
            *(const uint4*)(qkv + ((size_t)b * 1024 + n0 + r) * 1536 + hh * 64 + cc);
    }
    __syncthreads();
    const int dv = t & 63, rb = (t >> 6) * 8;
    for (int r = rb; r < rb + 8; r++) {
        float fa = 0.f;
#pragma unroll
        for (int kk = 0; kk < 64; kk++)
            fa += b2f(*(const short*)(const void*)(qs + r * 64 + kk)) * kt[kk * 64 + dv];
        const size_t idx = ((size_t)b * 1024 + n0 + r) * 512 + hh * 64 + dv;
        const float qv = b2f(*(const short*)(const void*)(qs + r * 64 + dv));
        xs[idx] = xs[idx] + fa + qv * __bfloat162float(vc[idx]);
    }
}

// ---------------- workspace layout (bytes) ----------------------------------
static constexpr int    BC       = 8;
static constexpr int    NCHUNK   = 4;
static constexpr size_t OFF_WQ   = 0;
static constexpr size_t OFF_W1   = 1572864;
static constexpr size_t OFF_W2   = 3670016;
static constexpr size_t OFF_CUR  = 5767168;
static constexpr size_t OFF_QKV  = 14155776;
static constexpr size_t OFF_KTVP = 39321600;
static constexpr size_t OFF_CSP  = 43515904;
static constexpr size_t OFF_KTV  = 43581440;
static constexpr size_t OFF_VC   = 44630016;
static constexpr size_t OFF_HG   = 14155776;   // over dead qkv region
static constexpr size_t OFF_H2   = 47710208;
static constexpr size_t WS_NEED  = 81264640;   // ~77.5MB

extern "C" void kernel_launch(void* const* d_in, const int* in_sizes, int n_in,
                              void* d_out, int out_size, void* d_ws, size_t ws_size,
                              hipStream_t stream)
{
    const float* x     = (const float*)d_in[0];
    const float* cpe_w = (const float*)d_in[1];
    const float* cpe_b = (const float*)d_in[2];
    const float* ln1_w = (const float*)d_in[3];
    const float* ln1_b = (const float*)d_in[4];
    const float* qkv_w = (const float*)d_in[5];
    const float* crpe_w= (const float*)d_in[6];
    const float* crpe_b= (const float*)d_in[7];
    const float* ln2_w = (const float*)d_in[8];
    const float* ln2_b = (const float*)d_in[9];
    const float* fc1_w = (const float*)d_in[10];
    const float* fc1_b = (const float*)d_in[11];
    const float* dw_w  = (const float*)d_in[12];
    const float* dw_b  = (const float*)d_in[13];
    const float* fc2_w = (const float*)d_in[14];
    const float* fc2_b = (const float*)d_in[15];
    float* spine = (float*)d_out;   // fp32 residual spine lives in d_out
    char* ws = (char*)d_ws;

    if (ws_size < WS_NEED) {
        diag_k<<<1, 1, 0, stream>>>(spine, (float)ws_size);
        return;
    }

    bf16*  wq   = (bf16*)(ws + OFF_WQ);
    bf16*  w1   = (bf16*)(ws + OFF_W1);
    bf16*  w2   = (bf16*)(ws + OFF_W2);
    bf16*  cur  = (bf16*)(ws + OFF_CUR);
    bf16*  qkv  = (bf16*)(ws + OFF_QKV);
    float* ktvp = (float*)(ws + OFF_KTVP);
    float* csp  = (float*)(ws + OFF_CSP);
    float* ktv  = (float*)(ws + OFF_KTV);
    bf16*  vc   = (bf16*)(ws + OFF_VC);
    bf16*  hg   = (bf16*)(ws + OFF_HG);
    bf16*  h2   = (bf16*)(ws + OFF_H2);

    // weights -> bf16
    f2bf_k<<<(1536 * 512 + 255) / 256, 256, 0, stream>>>(qkv_w, wq, 1536 * 512);
    f2bf_k<<<(2048 * 512 + 255) / 256, 256, 0, stream>>>(fc1_w, w1, 2048 * 512);
    f2bf_k<<<(2048 * 512 + 255) / 256, 256, 0, stream>>>(fc2_w, w2, 2048 * 512);

    // CPE (full batch): spine = x + dwconv(x) + cpe_b  (32 img x 8 cg x 4 bands)
    conv3_k<float, float, true><<<32 * 8 * 4, 256, 0, stream>>>(x, 512, 0, cpe_w, cpe_b, spine, 512, 3);

    const int Mc = BC * 1024;  // 8192 rows per chunk
    for (int c = 0; c < NCHUNK; c++) {
        float* xs = spine + (size_t)c * Mc * 512;
        // LN1
        ln_k<<<Mc, 64, 0, stream>>>(xs, ln1_w, ln1_b, cur);
        // qkv = cur @ qkv_w^T
        gemm_k<0><<<dim3(Mc / 128, 12), 256, 0, stream>>>(cur, wq, nullptr, nullptr, qkv, nullptr, Mc, 1536, 512);
        // ktv partials + reduce
        ktv_part_k<<<BC * 8 * 4, 256, 0, stream>>>(qkv, ktvp, csp);
        ktv_red_k<<<BC * 8, 256, 0, stream>>>(ktvp, csp, ktv);
        // crpe conv on v (8 img x 8 cg x 4 bands)
        conv3_k<bf16, bf16, false><<<BC * 8 * 4, 256, 0, stream>>>(qkv, 1536, 1024, crpe_w, crpe_b, vc, 512, 3);
        // xs += q@ktv + q*vconv (in place)
        attnout_k<<<BC * 8 * 32, 256, 0, stream>>>(xs, qkv, ktv, vc);
        // LN2
        ln_k<<<Mc, 64, 0, stream>>>(xs, ln2_w, ln2_b, cur);
        // fc1 + gelu
        gemm_k<1><<<dim3(Mc / 128, 16), 256, 0, stream>>>(cur, w1, fc1_b, nullptr, hg, nullptr, Mc, 2048, 512);
        // hidden dwconv residual (8 img x 32 cg x 4 bands)
        conv3_k<bf16, bf16, true><<<BC * 32 * 4, 256, 0, stream>>>(hg, 2048, 0, dw_w, dw_b, h2, 2048, 5);
        // xs += h2 @ fc2_w^T + fc2_b (in place)
        gemm_k<2><<<dim3(Mc / 128, 4), 256, 0, stream>>>(h2, w2, fc2_b, xs, nullptr, xs, Mc, 512, 2048);
    }
}

// Round 5
// 843.304 us; speedup vs baseline: 4.2246x; 1.1294x over previous
//
#include <hip/hip_runtime.h>
#include <hip/hip_bf16.h>

using bf16 = __hip_bfloat16;
using s16x4 = __attribute__((ext_vector_type(4))) short;
using s16x8 = __attribute__((ext_vector_type(8))) short;
using f32x4 = __attribute__((ext_vector_type(4))) float;

#define DI __device__ __forceinline__

DI float b2f(short s) { union { unsigned u; float f; } z; z.u = ((unsigned)(unsigned short)s) << 16; return z.f; }

DI float gelu_f(float x) { return 0.5f * x * (1.f + erff(x * 0.7071067811865475f)); }

DI void stf(float* p, float v) { *p = v; }
DI void stf(bf16* p, float v) { *p = __float2bfloat16(v); }

// load 8 contiguous values as float
DI void ld8(const bf16* p, float* f) {
    s16x8 x = *(const s16x8*)(const void*)p;
#pragma unroll
    for (int c = 0; c < 8; c++) f[c] = b2f(x[c]);
}
DI void ld8(const float* p, float* f) {
    float4 a = *(const float4*)p, b = *(const float4*)(p + 4);
    f[0]=a.x; f[1]=a.y; f[2]=a.z; f[3]=a.w; f[4]=b.x; f[5]=b.y; f[6]=b.z; f[7]=b.w;
}

// async global->LDS, 16B per lane; LDS dest = wave-uniform base + lane*16
typedef const __attribute__((address_space(1))) void* gp_t;
typedef __attribute__((address_space(3))) void* lp_t;
DI void gload_lds16(const void* g, void* l) {
    __builtin_amdgcn_global_load_lds((gp_t)g, (lp_t)l, 16, 0, 0);
}

// ---------------- diagnostic: encode ws_size into output ----------------
__global__ void diag_k(float* out, float v) { out[0] = v; }

// ---------------- fp32 -> bf16 weight conversion ----------------
__global__ void f2bf_k(const float* __restrict__ in, bf16* __restrict__ out, int n) {
    int i = blockIdx.x * 256 + threadIdx.x;
    if (i < n) out[i] = __float2bfloat16(in[i]);
}

// ---------------- depthwise 3x3 conv v3: coalesced rolling-row --------------
DI void tap10(const float* r, float w0, float w1, float w2, float* acc) {
#pragma unroll
    for (int i = 0; i < 8; i++)
        acc[i] += w0 * r[i] + w1 * r[i + 1] + w2 * r[i + 2];
}

template <typename TI, typename TO, bool RESID>
__global__ __launch_bounds__(256) void conv3_k(
    const TI* in, long rs, long coff,
    const float* __restrict__ w, const float* __restrict__ bias,
    TO* out, long ors, int gshift)
{
    __shared__ float buf[2][64][34];
    const int t = threadIdx.x;
    const int band = blockIdx.x & 3;
    const int cg = (blockIdx.x >> 2) & ((1 << gshift) - 1);
    const int img = blockIdx.x >> (2 + gshift);
    const int y0 = band * 8;

    const int spx = t >> 3;          // pixel 0..31
    const int sce = (t & 7) * 8;     // channel elem 0..56
    const TI* gsrc = in + ((long)img << 10) * rs + coff + (long)cg * 64 + sce;

    const int c = t & 63;            // channel within group
    const int xg = t >> 6;           // x-octet 0..3
    const int xb = xg * 8;

    const int gch = (cg << 6) + c;
    float wv9[9];
#pragma unroll
    for (int j = 0; j < 9; j++) wv9[j] = w[gch * 9 + j];
    const float bw = bias[gch];

    auto stage = [&](int row) {
        float f[8];
        ld8(gsrc + (long)(row * 32 + spx) * rs, f);
        float* d = &buf[row & 1][0][0];
#pragma unroll
        for (int k = 0; k < 8; k++) d[(sce + k) * 34 + spx] = f[k];
    };
    auto slice = [&](int row, float* r) {
        const float* s = &buf[row & 1][c][0];
        r[0] = (xb == 0) ? 0.f : s[xb - 1];
#pragma unroll
        for (int i = 0; i < 4; i++) {
            float2 v = *(const float2*)(s + xb + 2 * i);
            r[1 + 2 * i] = v.x; r[2 + 2 * i] = v.y;
        }
        r[9] = (xb + 8 >= 32) ? 0.f : s[xb + 8];
    };

    float r0[10], r1[10], r2[10];
    if (y0 > 0) stage(y0 - 1);
    __syncthreads();
    if (y0 > 0) slice(y0 - 1, r0);
    else {
#pragma unroll
        for (int i = 0; i < 10; i++) r0[i] = 0.f;
    }
    stage(y0);
    __syncthreads();
    slice(y0, r1);

    for (int y = y0; y < y0 + 8; ++y) {
        const int yn = y + 1;
        if (yn <= 31) stage(yn);
        __syncthreads();
        if (yn <= 31) slice(yn, r2);
        else {
#pragma unroll
            for (int i = 0; i < 10; i++) r2[i] = 0.f;
        }
        float acc[8];
#pragma unroll
        for (int i = 0; i < 8; i++) acc[i] = bw;
        tap10(r0, wv9[0], wv9[1], wv9[2], acc);
        tap10(r1, wv9[3], wv9[4], wv9[5], acc);
        tap10(r2, wv9[6], wv9[7], wv9[8], acc);
        if (RESID) {
#pragma unroll
            for (int i = 0; i < 8; i++) acc[i] += r1[i + 1];
        }
        TO* o = out + ((long)(img * 1024 + y * 32 + xb)) * ors + (cg << 6) + c;
#pragma unroll
        for (int i = 0; i < 8; i++) stf(o + (long)i * ors, acc[i]);
#pragma unroll
        for (int i = 0; i < 10; i++) { r0[i] = r1[i]; r1[i] = r2[i]; }
    }
}

// ---------------- LayerNorm over C=512, fp32 in -> bf16 out ----------------
__global__ __launch_bounds__(64) void ln_k(const float* __restrict__ x,
                                           const float* __restrict__ w,
                                           const float* __restrict__ bp,
                                           bf16* __restrict__ out)
{
    const size_t row = blockIdx.x;
    const float* xr = x + row * 512;
    const int t = threadIdx.x;
    alignas(16) float v[8];
    *(float4*)&v[0] = *(const float4*)(xr + t * 8);
    *(float4*)&v[4] = *(const float4*)(xr + t * 8 + 4);
    float s = 0.f;
#pragma unroll
    for (int j = 0; j < 8; j++) s += v[j];
#pragma unroll
    for (int mm = 32; mm; mm >>= 1) s += __shfl_xor(s, mm);
    const float mu = s * (1.f / 512.f);
    float q = 0.f;
#pragma unroll
    for (int j = 0; j < 8; j++) { v[j] -= mu; q += v[j] * v[j]; }
#pragma unroll
    for (int mm = 32; mm; mm >>= 1) q += __shfl_xor(q, mm);
    const float rstd = rsqrtf(q * (1.f / 512.f) + 1e-6f);
    alignas(16) float wv[8], bv[8];
    *(float4*)&wv[0] = *(const float4*)(w + t * 8);
    *(float4*)&wv[4] = *(const float4*)(w + t * 8 + 4);
    *(float4*)&bv[0] = *(const float4*)(bp + t * 8);
    *(float4*)&bv[4] = *(const float4*)(bp + t * 8 + 4);
    alignas(16) bf16 o[8];
#pragma unroll
    for (int j = 0; j < 8; j++) o[j] = __float2bfloat16(v[j] * rstd * wv[j] + bv[j]);
    *(uint4*)(out + row * 512 + t * 8) = *(const uint4*)o;
}

// ---------------- bf16 MFMA GEMM: C[M,N] = A[M,K] * Bw[N,K]^T ----------------
// Double-buffered LDS + global_load_lds, XOR-swizzled (slot ^= (row>>1)&3) on
// both the per-lane global source and the ds_read address (LDS stays linear).
// 2-phase: ds_read(cur) -> issue STAGE(next) -> MFMA -> one barrier per tile.
// EPI 0: store bf16. EPI 1: +bias, gelu -> bf16. EPI 2: +bias +resid -> fp32.
template <int EPI, int BN>
__global__ __launch_bounds__(256) void gemm_k(
    const bf16* __restrict__ A, const bf16* __restrict__ Bw,
    const float* __restrict__ bias, const float* resid,
    bf16* __restrict__ outb, float* outf,
    int M, int Nn, int K)
{
    constexpr int WC = (BN == 128) ? 2 : 1;       // wave cols
    constexpr int WR = 4 / WC;                    // wave rows
    constexpr int MI = 128 / (16 * WR);           // frag rows/wave: 4 or 2
    constexpr int NJ = BN / (16 * WC);            // frag cols/wave: 4
    __shared__ __align__(16) short As[2][128 * 32];
    __shared__ __align__(16) short Bs[2][BN * 32];
    const int t = threadIdx.x;
    const int m0 = blockIdx.x * 128;
    const int n0 = blockIdx.y * BN;
    const int lane = t & 63;
    const int wv = t >> 6;
    const int wr = (WC == 2) ? (wv >> 1) : wv;
    const int wc = (WC == 2) ? (wv & 1) : 0;
    const int lr = lane & 15, lg = lane >> 4;

    f32x4 acc[MI][NJ] = {};

    // staging: lane l fills LDS row = base + (l>>2), slot = l&3 (linear dest).
    // source k pre-swizzled so LDS[row][s] = global slot s ^ ((row>>1)&3).
    const int sk = 8 * ((lane & 3) ^ ((lane >> 3) & 3));
    const int arow = wv * 32 + (lane >> 2);
    const bf16* Ag0 = A + (size_t)(m0 + arow) * K + sk;
    const bf16* Ag1 = Ag0 + (size_t)16 * K;
    const int brow = (BN == 128) ? arow : (wv * 16 + (lane >> 2));
    const bf16* Bg0 = Bw + (size_t)(n0 + brow) * K + sk;
    const bf16* Bg1 = Bg0 + (size_t)16 * K;   // used only when BN==128

    const int rsw = (lr >> 1) & 3;            // read-side swizzle (const/lane)

    auto STAGE = [&](int buf, int k0) {
        gload_lds16(Ag0 + k0, (char*)&As[buf][0] + wv * 2048);
        gload_lds16(Ag1 + k0, (char*)&As[buf][0] + wv * 2048 + 1024);
        if constexpr (BN == 128) {
            gload_lds16(Bg0 + k0, (char*)&Bs[buf][0] + wv * 2048);
            gload_lds16(Bg1 + k0, (char*)&Bs[buf][0] + wv * 2048 + 1024);
        } else {
            gload_lds16(Bg0 + k0, (char*)&Bs[buf][0] + wv * 1024);
        }
    };

    STAGE(0, 0);
    __syncthreads();
    const int KT = K / 32;
    int cur = 0;
    for (int kt = 0; kt < KT; ++kt) {
        s16x8 aF[MI], bF[NJ];
#pragma unroll
        for (int i = 0; i < MI; i++) {
            const int R = wr * (128 / WR) + i * 16 + lr;
            aF[i] = *(const s16x8*)(&As[cur][0] + R * 32 + ((lg ^ rsw) << 3));
        }
#pragma unroll
        for (int j = 0; j < NJ; j++) {
            const int R = wc * 64 + j * 16 + lr;
            bF[j] = *(const s16x8*)(&Bs[cur][0] + R * 32 + ((lg ^ rsw) << 3));
        }
        if (kt + 1 < KT) STAGE(cur ^ 1, (kt + 1) * 32);
#pragma unroll
        for (int i = 0; i < MI; i++)
#pragma unroll
            for (int j = 0; j < NJ; j++)
                acc[i][j] = __builtin_amdgcn_mfma_f32_16x16x32_bf16(aF[i], bF[j], acc[i][j], 0, 0, 0);
        __syncthreads();
        cur ^= 1;
    }

#pragma unroll
    for (int i = 0; i < MI; i++) {
#pragma unroll
        for (int j = 0; j < NJ; j++) {
#pragma unroll
            for (int r = 0; r < 4; r++) {
                const int row = m0 + wr * (128 / WR) + i * 16 + lg * 4 + r;
                const int col = n0 + wc * 64 + j * 16 + lr;
                float v = acc[i][j][r];
                if (EPI > 0) v += bias[col];
                const size_t idx = (size_t)row * Nn + col;
                if (EPI == 0) outb[idx] = __float2bfloat16(v);
                else if (EPI == 1) outb[idx] = __float2bfloat16(gelu_f(v));
                else outf[idx] = v + resid[idx];
            }
        }
    }
}

// ---------------- ktv partials: no max-subtraction softmax -------------------
__global__ __launch_bounds__(256) void ktv_part_k(const bf16* __restrict__ qkv,
                                                  float* __restrict__ ktvp,
                                                  float* __restrict__ csp)
{
    const int b = blockIdx.x >> 5;
    const int hh = (blockIdx.x >> 2) & 7;
    const int sp = blockIdx.x & 3;
    const bf16* kb = qkv + (size_t)b * 1024 * 1536 + 512 + hh * 64;
    const bf16* vb = kb + 512;
    __shared__ __align__(16) bf16 Ks[16 * 64];
    __shared__ __align__(16) bf16 Vs[16 * 64];
    const int t = threadIdx.x;
    const int kk = t & 63, vg = t >> 6;
    float acc[16] = {};
    float psum = 0.f;
    const int sr = t >> 4, sc = (t & 15) * 4;
    for (int n0 = sp * 256; n0 < sp * 256 + 256; n0 += 16) {
        __syncthreads();
        *(s16x4*)(void*)(Ks + sr * 64 + sc) = *(const s16x4*)(const void*)(kb + (size_t)(n0 + sr) * 1536 + sc);
        *(s16x4*)(void*)(Vs + sr * 64 + sc) = *(const s16x4*)(const void*)(vb + (size_t)(n0 + sr) * 1536 + sc);
        __syncthreads();
#pragma unroll
        for (int i = 0; i < 16; i++) {
            const float p = __expf(b2f(*(const short*)(const void*)(Ks + i * 64 + kk)));
            psum += p;
            float vv[16];
            ld8(Vs + i * 64 + vg * 16, vv);
            ld8(Vs + i * 64 + vg * 16 + 8, vv + 8);
#pragma unroll
            for (int j = 0; j < 16; j++) acc[j] += p * vv[j];
        }
    }
    const int bh4 = (b * 8 + hh) * 4 + sp;
    float* o = ktvp + (size_t)bh4 * 4096 + kk * 64 + vg * 16;
#pragma unroll
    for (int j = 0; j < 16; j++) o[j] = acc[j];
    if (vg == 0) csp[bh4 * 64 + kk] = psum;
}

// ---------------- ktv reduce: fold 4 partials, scale by 0.125/csum ----------
__global__ __launch_bounds__(256) void ktv_red_k(const float* __restrict__ ktvp,
                                                 const float* __restrict__ csp,
                                                 float* __restrict__ ktv)
{
    const int bh = blockIdx.x;
    const int t = threadIdx.x;
#pragma unroll
    for (int i = 0; i < 16; i++) {
        const int e = t + 256 * i;
        const int kk = e >> 6;
        float cs = 0.f, v = 0.f;
#pragma unroll
        for (int sp = 0; sp < 4; sp++) {
            cs += csp[(bh * 4 + sp) * 64 + kk];
            v += ktvp[(size_t)(bh * 4 + sp) * 4096 + e];
        }
        ktv[(size_t)bh * 4096 + e] = v * (0.125f / cs);
    }
}

// ---------------- xs += q @ ktv_scaled + q * vconv  (in place) --------------
__global__ __launch_bounds__(256) void attnout_k(
    float* xs, const bf16* __restrict__ qkv,
    const float* __restrict__ ktv, const bf16* __restrict__ vc)
{
    const int nc = blockIdx.x & 31, hh = (blockIdx.x >> 5) & 7, b = blockIdx.x >> 8;
    __shared__ __align__(16) float kt[64 * 64];
    __shared__ __align__(16) bf16 qs[32 * 64];
    const int t = threadIdx.x;
    const float4* ksrc = (const float4*)(ktv + (size_t)(b * 8 + hh) * 4096);
    for (int u = t; u < 1024; u += 256) ((float4*)kt)[u] = ksrc[u];
    const int n0 = nc * 32;
    {
        const int r = t >> 3, cc = (t & 7) * 8;
        *(uint4*)(qs + r * 64 + cc) =
            *(const uint4*)(qkv + ((size_t)b * 1024 + n0 + r) * 1536 + hh * 64 + cc);
    }
    __syncthreads();
    const int dv = t & 63, rb = (t >> 6) * 8;
    for (int r = rb; r < rb + 8; r++) {
        float fa = 0.f;
#pragma unroll
        for (int kk = 0; kk < 64; kk++)
            fa += b2f(*(const short*)(const void*)(qs + r * 64 + kk)) * kt[kk * 64 + dv];
        const size_t idx = ((size_t)b * 1024 + n0 + r) * 512 + hh * 64 + dv;
        const float qv = b2f(*(const short*)(const void*)(qs + r * 64 + dv));
        xs[idx] = xs[idx] + fa + qv * __bfloat162float(vc[idx]);
    }
}

// ---------------- workspace layout (bytes) ----------------------------------
static constexpr int    BC       = 8;
static constexpr int    NCHUNK   = 4;
static constexpr size_t OFF_WQ   = 0;
static constexpr size_t OFF_W1   = 1572864;
static constexpr size_t OFF_W2   = 3670016;
static constexpr size_t OFF_CUR  = 5767168;
static constexpr size_t OFF_QKV  = 14155776;
static constexpr size_t OFF_KTVP = 39321600;
static constexpr size_t OFF_CSP  = 43515904;
static constexpr size_t OFF_KTV  = 43581440;
static constexpr size_t OFF_VC   = 44630016;
static constexpr size_t OFF_HG   = 14155776;   // over dead qkv region
static constexpr size_t OFF_H2   = 47710208;
static constexpr size_t WS_NEED  = 81264640;   // ~77.5MB

extern "C" void kernel_launch(void* const* d_in, const int* in_sizes, int n_in,
                              void* d_out, int out_size, void* d_ws, size_t ws_size,
                              hipStream_t stream)
{
    const float* x     = (const float*)d_in[0];
    const float* cpe_w = (const float*)d_in[1];
    const float* cpe_b = (const float*)d_in[2];
    const float* ln1_w = (const float*)d_in[3];
    const float* ln1_b = (const float*)d_in[4];
    const float* qkv_w = (const float*)d_in[5];
    const float* crpe_w= (const float*)d_in[6];
    const float* crpe_b= (const float*)d_in[7];
    const float* ln2_w = (const float*)d_in[8];
    const float* ln2_b = (const float*)d_in[9];
    const float* fc1_w = (const float*)d_in[10];
    const float* fc1_b = (const float*)d_in[11];
    const float* dw_w  = (const float*)d_in[12];
    const float* dw_b  = (const float*)d_in[13];
    const float* fc2_w = (const float*)d_in[14];
    const float* fc2_b = (const float*)d_in[15];
    float* spine = (float*)d_out;   // fp32 residual spine lives in d_out
    char* ws = (char*)d_ws;

    if (ws_size < WS_NEED) {
        diag_k<<<1, 1, 0, stream>>>(spine, (float)ws_size);
        return;
    }

    bf16*  wq   = (bf16*)(ws + OFF_WQ);
    bf16*  w1   = (bf16*)(ws + OFF_W1);
    bf16*  w2   = (bf16*)(ws + OFF_W2);
    bf16*  cur  = (bf16*)(ws + OFF_CUR);
    bf16*  qkv  = (bf16*)(ws + OFF_QKV);
    float* ktvp = (float*)(ws + OFF_KTVP);
    float* csp  = (float*)(ws + OFF_CSP);
    float* ktv  = (float*)(ws + OFF_KTV);
    bf16*  vc   = (bf16*)(ws + OFF_VC);
    bf16*  hg   = (bf16*)(ws + OFF_HG);
    bf16*  h2   = (bf16*)(ws + OFF_H2);

    // weights -> bf16
    f2bf_k<<<(1536 * 512 + 255) / 256, 256, 0, stream>>>(qkv_w, wq, 1536 * 512);
    f2bf_k<<<(2048 * 512 + 255) / 256, 256, 0, stream>>>(fc1_w, w1, 2048 * 512);
    f2bf_k<<<(2048 * 512 + 255) / 256, 256, 0, stream>>>(fc2_w, w2, 2048 * 512);

    // CPE (full batch): spine = x + dwconv(x) + cpe_b  (32 img x 8 cg x 4 bands)
    conv3_k<float, float, true><<<32 * 8 * 4, 256, 0, stream>>>(x, 512, 0, cpe_w, cpe_b, spine, 512, 3);

    const int Mc = BC * 1024;  // 8192 rows per chunk
    for (int c = 0; c < NCHUNK; c++) {
        float* xs = spine + (size_t)c * Mc * 512;
        // LN1
        ln_k<<<Mc, 64, 0, stream>>>(xs, ln1_w, ln1_b, cur);
        // qkv = cur @ qkv_w^T
        gemm_k<0, 128><<<dim3(Mc / 128, 12), 256, 0, stream>>>(cur, wq, nullptr, nullptr, qkv, nullptr, Mc, 1536, 512);
        // ktv partials + reduce
        ktv_part_k<<<BC * 8 * 4, 256, 0, stream>>>(qkv, ktvp, csp);
        ktv_red_k<<<BC * 8, 256, 0, stream>>>(ktvp, csp, ktv);
        // crpe conv on v (8 img x 8 cg x 4 bands)
        conv3_k<bf16, bf16, false><<<BC * 8 * 4, 256, 0, stream>>>(qkv, 1536, 1024, crpe_w, crpe_b, vc, 512, 3);
        // xs += q@ktv + q*vconv (in place)
        attnout_k<<<BC * 8 * 32, 256, 0, stream>>>(xs, qkv, ktv, vc);
        // LN2
        ln_k<<<Mc, 64, 0, stream>>>(xs, ln2_w, ln2_b, cur);
        // fc1 + gelu
        gemm_k<1, 128><<<dim3(Mc / 128, 16), 256, 0, stream>>>(cur, w1, fc1_b, nullptr, hg, nullptr, Mc, 2048, 512);
        // hidden dwconv residual (8 img x 32 cg x 4 bands)
        conv3_k<bf16, bf16, true><<<BC * 32 * 4, 256, 0, stream>>>(hg, 2048, 0, dw_w, dw_b, h2, 2048, 5);
        // xs += h2 @ fc2_w^T + fc2_b (in place), 128x64 tiles -> 512 blocks
        gemm_k<2, 64><<<dim3(Mc / 128, 8), 256, 0, stream>>>(h2, w2, fc2_b, xs, nullptr, xs, Mc, 512, 2048);
    }
}

// Round 6
// 822.124 us; speedup vs baseline: 4.3334x; 1.0258x over previous
//
#include <hip/hip_runtime.h>
#include <hip/hip_bf16.h>

using bf16 = __hip_bfloat16;
using s16x4 = __attribute__((ext_vector_type(4))) short;
using s16x8 = __attribute__((ext_vector_type(8))) short;
using f32x4 = __attribute__((ext_vector_type(4))) float;

#define DI __device__ __forceinline__

DI float b2f(short s) { union { unsigned u; float f; } z; z.u = ((unsigned)(unsigned short)s) << 16; return z.f; }
DI short f2b(float f) { bf16 t = __float2bfloat16(f); return *(short*)&t; }

// fast gelu: tanh form, |err| ~1e-3 (absolute), far under threshold
DI float gelu_f(float x) {
    const float t = 0.7978845608f * x * (1.f + 0.044715f * x * x);
    const float e = __expf(2.f * t);
    const float th = 1.f - 2.f / (e + 1.f);
    return 0.5f * x * (1.f + th);
}

DI void stf(float* p, float v) { *p = v; }
DI void stf(bf16* p, float v) { *p = __float2bfloat16(v); }

DI void ld8(const bf16* p, float* f) {
    s16x8 x = *(const s16x8*)(const void*)p;
#pragma unroll
    for (int c = 0; c < 8; c++) f[c] = b2f(x[c]);
}
DI void ld8(const float* p, float* f) {
    float4 a = *(const float4*)p, b = *(const float4*)(p + 4);
    f[0]=a.x; f[1]=a.y; f[2]=a.z; f[3]=a.w; f[4]=b.x; f[5]=b.y; f[6]=b.z; f[7]=b.w;
}

typedef const __attribute__((address_space(1))) void* gp_t;
typedef __attribute__((address_space(3))) void* lp_t;
DI void gload_lds16(const void* g, void* l) {
    __builtin_amdgcn_global_load_lds((gp_t)g, (lp_t)l, 16, 0, 0);
}

// ---------------- diagnostic ----------------
__global__ void diag_k(float* out, float v) { out[0] = v; }

// ---------------- fp32 -> bf16 weight conversion (8/thread) ----------------
__global__ void f2bf_k(const float* __restrict__ in, bf16* __restrict__ out, int n) {
    int i = (blockIdx.x * 256 + threadIdx.x) * 8;
    if (i >= n) return;
    float f[8];
    ld8(in + i, f);
    s16x8 o;
#pragma unroll
    for (int c = 0; c < 8; c++) o[c] = f2b(f[c]);
    *(s16x8*)(void*)(out + i) = o;
}

// ---------------- depthwise 3x3 conv: coalesced rolling-row ----------------
DI void tap10(const float* r, float w0, float w1, float w2, float* acc) {
#pragma unroll
    for (int i = 0; i < 8; i++)
        acc[i] += w0 * r[i] + w1 * r[i + 1] + w2 * r[i + 2];
}

template <typename TI, typename TO, bool RESID>
__global__ __launch_bounds__(256) void conv3_k(
    const TI* in, long rs, long coff,
    const float* __restrict__ w, const float* __restrict__ bias,
    TO* out, long ors, int gshift)
{
    __shared__ float buf[2][64][34];
    const int t = threadIdx.x;
    const int band = blockIdx.x & 3;
    const int cg = (blockIdx.x >> 2) & ((1 << gshift) - 1);
    const int img = blockIdx.x >> (2 + gshift);
    const int y0 = band * 8;

    const int spx = t >> 3;
    const int sce = (t & 7) * 8;
    const TI* gsrc = in + ((long)img << 10) * rs + coff + (long)cg * 64 + sce;

    const int c = t & 63;
    const int xg = t >> 6;
    const int xb = xg * 8;

    const int gch = (cg << 6) + c;
    float wv9[9];
#pragma unroll
    for (int j = 0; j < 9; j++) wv9[j] = w[gch * 9 + j];
    const float bw = bias[gch];

    auto stage = [&](int row) {
        float f[8];
        ld8(gsrc + (long)(row * 32 + spx) * rs, f);
        float* d = &buf[row & 1][0][0];
#pragma unroll
        for (int k = 0; k < 8; k++) d[(sce + k) * 34 + spx] = f[k];
    };
    auto slice = [&](int row, float* r) {
        const float* s = &buf[row & 1][c][0];
        r[0] = (xb == 0) ? 0.f : s[xb - 1];
#pragma unroll
        for (int i = 0; i < 4; i++) {
            float2 v = *(const float2*)(s + xb + 2 * i);
            r[1 + 2 * i] = v.x; r[2 + 2 * i] = v.y;
        }
        r[9] = (xb + 8 >= 32) ? 0.f : s[xb + 8];
    };

    float r0[10], r1[10], r2[10];
    if (y0 > 0) stage(y0 - 1);
    __syncthreads();
    if (y0 > 0) slice(y0 - 1, r0);
    else {
#pragma unroll
        for (int i = 0; i < 10; i++) r0[i] = 0.f;
    }
    stage(y0);
    __syncthreads();
    slice(y0, r1);

    for (int y = y0; y < y0 + 8; ++y) {
        const int yn = y + 1;
        if (yn <= 31) stage(yn);
        __syncthreads();
        if (yn <= 31) slice(yn, r2);
        else {
#pragma unroll
            for (int i = 0; i < 10; i++) r2[i] = 0.f;
        }
        float acc[8];
#pragma unroll
        for (int i = 0; i < 8; i++) acc[i] = bw;
        tap10(r0, wv9[0], wv9[1], wv9[2], acc);
        tap10(r1, wv9[3], wv9[4], wv9[5], acc);
        tap10(r2, wv9[6], wv9[7], wv9[8], acc);
        if (RESID) {
#pragma unroll
            for (int i = 0; i < 8; i++) acc[i] += r1[i + 1];
        }
        TO* o = out + ((long)(img * 1024 + y * 32 + xb)) * ors + (cg << 6) + c;
#pragma unroll
        for (int i = 0; i < 8; i++) stf(o + (long)i * ors, acc[i]);
#pragma unroll
        for (int i = 0; i < 10; i++) { r0[i] = r1[i]; r1[i] = r2[i]; }
    }
}

// ---------------- LayerNorm over C=512, fp32 in -> bf16 out ----------------
__global__ __launch_bounds__(64) void ln_k(const float* __restrict__ x,
                                           const float* __restrict__ w,
                                           const float* __restrict__ bp,
                                           bf16* __restrict__ out)
{
    const size_t row = blockIdx.x;
    const float* xr = x + row * 512;
    const int t = threadIdx.x;
    alignas(16) float v[8];
    *(float4*)&v[0] = *(const float4*)(xr + t * 8);
    *(float4*)&v[4] = *(const float4*)(xr + t * 8 + 4);
    float s = 0.f;
#pragma unroll
    for (int j = 0; j < 8; j++) s += v[j];
#pragma unroll
    for (int mm = 32; mm; mm >>= 1) s += __shfl_xor(s, mm);
    const float mu = s * (1.f / 512.f);
    float q = 0.f;
#pragma unroll
    for (int j = 0; j < 8; j++) { v[j] -= mu; q += v[j] * v[j]; }
#pragma unroll
    for (int mm = 32; mm; mm >>= 1) q += __shfl_xor(q, mm);
    const float rstd = rsqrtf(q * (1.f / 512.f) + 1e-6f);
    alignas(16) float wv[8], bv[8];
    *(float4*)&wv[0] = *(const float4*)(w + t * 8);
    *(float4*)&wv[4] = *(const float4*)(w + t * 8 + 4);
    *(float4*)&bv[0] = *(const float4*)(bp + t * 8);
    *(float4*)&bv[4] = *(const float4*)(bp + t * 8 + 4);
    alignas(16) bf16 o[8];
#pragma unroll
    for (int j = 0; j < 8; j++) o[j] = __float2bfloat16(v[j] * rstd * wv[j] + bv[j]);
    *(uint4*)(out + row * 512 + t * 8) = *(const uint4*)o;
}

// ---------------- bf16 MFMA GEMM: C[M,N] = A[M,K] * Bw[N,K]^T ----------------
// 3-buffer LDS pipeline, counted vmcnt (never 0 in main loop), one raw
// s_barrier per K-step. XOR swizzle (slot ^= (row>>1)&3) pre-applied on the
// per-lane GLOBAL source; LDS dest linear (global_load_lds requirement);
// same XOR on the ds_read side. EPI 0: bf16. 1: +bias,gelu->bf16. 2: +bias+resid->fp32.
template <int EPI, int BN>
__global__ __launch_bounds__(256) void gemm_k(
    const bf16* __restrict__ A, const bf16* __restrict__ Bw,
    const float* __restrict__ bias, const float* resid,
    bf16* __restrict__ outb, float* outf,
    int M, int Nn, int K)
{
    constexpr int WC = (BN == 128) ? 2 : 1;
    constexpr int WR = 4 / WC;
    constexpr int MI = 128 / (16 * WR);
    constexpr int NJ = BN / (16 * WC);
    __shared__ __align__(16) short As[3][128 * 32];
    __shared__ __align__(16) short Bs[3][BN * 32];
    const int t = threadIdx.x;
    const int m0 = blockIdx.x * 128;
    const int n0 = blockIdx.y * BN;
    const int lane = t & 63;
    const int wv = t >> 6;
    const int wr = (WC == 2) ? (wv >> 1) : wv;
    const int wc = (WC == 2) ? (wv & 1) : 0;
    const int lr = lane & 15, lg = lane >> 4;

    f32x4 acc[MI][NJ] = {};

    const int sk = 8 * ((lane & 3) ^ ((lane >> 3) & 3));
    const int arow = wv * 32 + (lane >> 2);
    const bf16* Ag0 = A + (size_t)(m0 + arow) * K + sk;
    const bf16* Ag1 = Ag0 + (size_t)16 * K;
    const int brow = (BN == 128) ? arow : (wv * 16 + (lane >> 2));
    const bf16* Bg0 = Bw + (size_t)(n0 + brow) * K + sk;
    const bf16* Bg1 = Bg0 + (size_t)16 * K;

    const int rsw = (lr >> 1) & 3;

    auto STAGE = [&](int buf, int k0) {
        gload_lds16(Ag0 + k0, (char*)&As[buf][0] + wv * 2048);
        gload_lds16(Ag1 + k0, (char*)&As[buf][0] + wv * 2048 + 1024);
        if constexpr (BN == 128) {
            gload_lds16(Bg0 + k0, (char*)&Bs[buf][0] + wv * 2048);
            gload_lds16(Bg1 + k0, (char*)&Bs[buf][0] + wv * 2048 + 1024);
        } else {
            gload_lds16(Bg0 + k0, (char*)&Bs[buf][0] + wv * 1024);
        }
    };

    auto COMPUTE = [&](int buf) {
        s16x8 aF[MI], bF[NJ];
#pragma unroll
        for (int i = 0; i < MI; i++) {
            const int R = wr * (128 / WR) + i * 16 + lr;
            aF[i] = *(const s16x8*)(&As[buf][0] + R * 32 + ((lg ^ rsw) << 3));
        }
#pragma unroll
        for (int j = 0; j < NJ; j++) {
            const int R = wc * 64 + j * 16 + lr;
            bF[j] = *(const s16x8*)(&Bs[buf][0] + R * 32 + ((lg ^ rsw) << 3));
        }
#pragma unroll
        for (int i = 0; i < MI; i++)
#pragma unroll
            for (int j = 0; j < NJ; j++)
                acc[i][j] = __builtin_amdgcn_mfma_f32_16x16x32_bf16(aF[i], bF[j], acc[i][j], 0, 0, 0);
    };

    const int KT = K / 32;
    STAGE(0, 0);
    STAGE(1, 32);
    int cur = 0;
    for (int kt = 0; kt < KT - 1; ++kt) {
        // tile kt complete; tile kt+1 (LPS loads) may remain in flight
        if constexpr (BN == 128) asm volatile("s_waitcnt vmcnt(4)" ::: "memory");
        else                     asm volatile("s_waitcnt vmcnt(3)" ::: "memory");
        __builtin_amdgcn_s_barrier();
        if (kt + 2 < KT) {
            int s = cur + 2; if (s >= 3) s -= 3;
            STAGE(s, (kt + 2) * 32);
        }
        COMPUTE(cur);
        if (++cur == 3) cur = 0;
    }
    asm volatile("s_waitcnt vmcnt(0)" ::: "memory");
    __builtin_amdgcn_s_barrier();
    COMPUTE(cur);

#pragma unroll
    for (int i = 0; i < MI; i++) {
#pragma unroll
        for (int j = 0; j < NJ; j++) {
            const int col = n0 + wc * 64 + j * 16 + lr;
            const float bcol = (EPI > 0) ? bias[col] : 0.f;
#pragma unroll
            for (int r = 0; r < 4; r++) {
                const int row = m0 + wr * (128 / WR) + i * 16 + lg * 4 + r;
                float v = acc[i][j][r] + bcol;
                const size_t idx = (size_t)row * Nn + col;
                if (EPI == 0) outb[idx] = __float2bfloat16(v);
                else if (EPI == 1) outb[idx] = __float2bfloat16(gelu_f(v));
                else outf[idx] = v + resid[idx];
            }
        }
    }
}

// ---------------- ktv partials: no max-subtraction softmax -------------------
__global__ __launch_bounds__(256) void ktv_part_k(const bf16* __restrict__ qkv,
                                                  float* __restrict__ ktvp,
                                                  float* __restrict__ csp)
{
    const int b = blockIdx.x >> 5;
    const int hh = (blockIdx.x >> 2) & 7;
    const int sp = blockIdx.x & 3;
    const bf16* kb = qkv + (size_t)b * 1024 * 1536 + 512 + hh * 64;
    const bf16* vb = kb + 512;
    __shared__ __align__(16) bf16 Ks[16 * 64];
    __shared__ __align__(16) bf16 Vs[16 * 64];
    const int t = threadIdx.x;
    const int kk = t & 63, vg = t >> 6;
    float acc[16] = {};
    float psum = 0.f;
    const int sr = t >> 4, sc = (t & 15) * 4;
    for (int n0 = sp * 256; n0 < sp * 256 + 256; n0 += 16) {
        __syncthreads();
        *(s16x4*)(void*)(Ks + sr * 64 + sc) = *(const s16x4*)(const void*)(kb + (size_t)(n0 + sr) * 1536 + sc);
        *(s16x4*)(void*)(Vs + sr * 64 + sc) = *(const s16x4*)(const void*)(vb + (size_t)(n0 + sr) * 1536 + sc);
        __syncthreads();
#pragma unroll
        for (int i = 0; i < 16; i++) {
            const float p = __expf(b2f(*(const short*)(const void*)(Ks + i * 64 + kk)));
            psum += p;
            float vv[16];
            ld8(Vs + i * 64 + vg * 16, vv);
            ld8(Vs + i * 64 + vg * 16 + 8, vv + 8);
#pragma unroll
            for (int j = 0; j < 16; j++) acc[j] += p * vv[j];
        }
    }
    const int bh4 = (b * 8 + hh) * 4 + sp;
    float* o = ktvp + (size_t)bh4 * 4096 + kk * 64 + vg * 16;
#pragma unroll
    for (int j = 0; j < 16; j++) o[j] = acc[j];
    if (vg == 0) csp[bh4 * 64 + kk] = psum;
}

// ---------------- ktv reduce ----------
__global__ __launch_bounds__(256) void ktv_red_k(const float* __restrict__ ktvp,
                                                 const float* __restrict__ csp,
                                                 float* __restrict__ ktv)
{
    const int bh = blockIdx.x;
    const int t = threadIdx.x;
#pragma unroll
    for (int i = 0; i < 16; i++) {
        const int e = t + 256 * i;
        const int kk = e >> 6;
        float cs = 0.f, v = 0.f;
#pragma unroll
        for (int sp = 0; sp < 4; sp++) {
            cs += csp[(bh * 4 + sp) * 64 + kk];
            v += ktvp[(size_t)(bh * 4 + sp) * 4096 + e];
        }
        ktv[(size_t)bh * 4096 + e] = v * (0.125f / cs);
    }
}

// ---------------- xs += q @ ktv_scaled + q * vconv  (in place) --------------
__global__ __launch_bounds__(256) void attnout_k(
    float* xs, const bf16* __restrict__ qkv,
    const float* __restrict__ ktv, const bf16* __restrict__ vc)
{
    const int nc = blockIdx.x & 31, hh = (blockIdx.x >> 5) & 7, b = blockIdx.x >> 8;
    __shared__ __align__(16) float kt[64 * 64];
    __shared__ __align__(16) bf16 qs[32 * 64];
    const int t = threadIdx.x;
    const float4* ksrc = (const float4*)(ktv + (size_t)(b * 8 + hh) * 4096);
    for (int u = t; u < 1024; u += 256) ((float4*)kt)[u] = ksrc[u];
    const int n0 = nc * 32;
    {
        const int r = t >> 3, cc = (t & 7) * 8;
        *(uint4*)(qs + r * 64 + cc) =
            *(const uint4*)(qkv + ((size_t)b * 1024 + n0 + r) * 1536 + hh * 64 + cc);
    }
    __syncthreads();
    const int dv = t & 63, rb = (t >> 6) * 8;
    for (int r = rb; r < rb + 8; r++) {
        float fa = 0.f;
#pragma unroll
        for (int kk = 0; kk < 64; kk++)
            fa += b2f(*(const short*)(const void*)(qs + r * 64 + kk)) * kt[kk * 64 + dv];
        const size_t idx = ((size_t)b * 1024 + n0 + r) * 512 + hh * 64 + dv;
        const float qv = b2f(*(const short*)(const void*)(qs + r * 64 + dv));
        xs[idx] = xs[idx] + fa + qv * __bfloat162float(vc[idx]);
    }
}

// ---------------- workspace layout (bytes) ----------------------------------
static constexpr int    BC       = 8;
static constexpr int    NCHUNK   = 4;
static constexpr size_t OFF_WQ   = 0;
static constexpr size_t OFF_W1   = 1572864;
static constexpr size_t OFF_W2   = 3670016;
static constexpr size_t OFF_CUR  = 5767168;
static constexpr size_t OFF_QKV  = 14155776;
static constexpr size_t OFF_KTVP = 39321600;
static constexpr size_t OFF_CSP  = 43515904;
static constexpr size_t OFF_KTV  = 43581440;
static constexpr size_t OFF_VC   = 44630016;
static constexpr size_t OFF_HG   = 14155776;   // over dead qkv region
static constexpr size_t OFF_H2   = 47710208;
static constexpr size_t WS_NEED  = 81264640;   // ~77.5MB

extern "C" void kernel_launch(void* const* d_in, const int* in_sizes, int n_in,
                              void* d_out, int out_size, void* d_ws, size_t ws_size,
                              hipStream_t stream)
{
    const float* x     = (const float*)d_in[0];
    const float* cpe_w = (const float*)d_in[1];
    const float* cpe_b = (const float*)d_in[2];
    const float* ln1_w = (const float*)d_in[3];
    const float* ln1_b = (const float*)d_in[4];
    const float* qkv_w = (const float*)d_in[5];
    const float* crpe_w= (const float*)d_in[6];
    const float* crpe_b= (const float*)d_in[7];
    const float* ln2_w = (const float*)d_in[8];
    const float* ln2_b = (const float*)d_in[9];
    const float* fc1_w = (const float*)d_in[10];
    const float* fc1_b = (const float*)d_in[11];
    const float* dw_w  = (const float*)d_in[12];
    const float* dw_b  = (const float*)d_in[13];
    const float* fc2_w = (const float*)d_in[14];
    const float* fc2_b = (const float*)d_in[15];
    float* spine = (float*)d_out;
    char* ws = (char*)d_ws;

    if (ws_size < WS_NEED) {
        diag_k<<<1, 1, 0, stream>>>(spine, (float)ws_size);
        return;
    }

    bf16*  wq   = (bf16*)(ws + OFF_WQ);
    bf16*  w1   = (bf16*)(ws + OFF_W1);
    bf16*  w2   = (bf16*)(ws + OFF_W2);
    bf16*  cur  = (bf16*)(ws + OFF_CUR);
    bf16*  qkv  = (bf16*)(ws + OFF_QKV);
    float* ktvp = (float*)(ws + OFF_KTVP);
    float* csp  = (float*)(ws + OFF_CSP);
    float* ktv  = (float*)(ws + OFF_KTV);
    bf16*  vc   = (bf16*)(ws + OFF_VC);
    bf16*  hg   = (bf16*)(ws + OFF_HG);
    bf16*  h2   = (bf16*)(ws + OFF_H2);

    // weights -> bf16 (8 elems/thread)
    f2bf_k<<<(1536 * 512 / 8 + 255) / 256, 256, 0, stream>>>(qkv_w, wq, 1536 * 512);
    f2bf_k<<<(2048 * 512 / 8 + 255) / 256, 256, 0, stream>>>(fc1_w, w1, 2048 * 512);
    f2bf_k<<<(2048 * 512 / 8 + 255) / 256, 256, 0, stream>>>(fc2_w, w2, 2048 * 512);

    // CPE (full batch): spine = x + dwconv(x) + cpe_b
    conv3_k<float, float, true><<<32 * 8 * 4, 256, 0, stream>>>(x, 512, 0, cpe_w, cpe_b, spine, 512, 3);

    const int Mc = BC * 1024;
    for (int c = 0; c < NCHUNK; c++) {
        float* xs = spine + (size_t)c * Mc * 512;
        ln_k<<<Mc, 64, 0, stream>>>(xs, ln1_w, ln1_b, cur);
        gemm_k<0, 128><<<dim3(Mc / 128, 12), 256, 0, stream>>>(cur, wq, nullptr, nullptr, qkv, nullptr, Mc, 1536, 512);
        ktv_part_k<<<BC * 8 * 4, 256, 0, stream>>>(qkv, ktvp, csp);
        ktv_red_k<<<BC * 8, 256, 0, stream>>>(ktvp, csp, ktv);
        conv3_k<bf16, bf16, false><<<BC * 8 * 4, 256, 0, stream>>>(qkv, 1536, 1024, crpe_w, crpe_b, vc, 512, 3);
        attnout_k<<<BC * 8 * 32, 256, 0, stream>>>(xs, qkv, ktv, vc);
        ln_k<<<Mc, 64, 0, stream>>>(xs, ln2_w, ln2_b, cur);
        gemm_k<1, 128><<<dim3(Mc / 128, 16), 256, 0, stream>>>(cur, w1, fc1_b, nullptr, hg, nullptr, Mc, 2048, 512);
        conv3_k<bf16, bf16, true><<<BC * 32 * 4, 256, 0, stream>>>(hg, 2048, 0, dw_w, dw_b, h2, 2048, 5);
        gemm_k<2, 64><<<dim3(Mc / 128, 8), 256, 0, stream>>>(h2, w2, fc2_b, xs, nullptr, xs, Mc, 512, 2048);
    }
}

// Round 7
// 811.089 us; speedup vs baseline: 4.3924x; 1.0136x over previous
//
#include <hip/hip_runtime.h>
#include <hip/hip_bf16.h>

using bf16 = __hip_bfloat16;
using s16x4 = __attribute__((ext_vector_type(4))) short;
using s16x8 = __attribute__((ext_vector_type(8))) short;
using f32x4 = __attribute__((ext_vector_type(4))) float;

#define DI __device__ __forceinline__

DI float b2f(short s) { union { unsigned u; float f; } z; z.u = ((unsigned)(unsigned short)s) << 16; return z.f; }
DI short f2b(float f) { bf16 t = __float2bfloat16(f); return *(short*)&t; }

// fast gelu: tanh form, |err| ~1e-3 absolute, far under threshold
DI float gelu_f(float x) {
    const float t = 0.7978845608f * x * (1.f + 0.044715f * x * x);
    const float e = __expf(2.f * t);
    const float th = 1.f - 2.f / (e + 1.f);
    return 0.5f * x * (1.f + th);
}

DI void ld8(const bf16* p, float* f) {
    s16x8 x = *(const s16x8*)(const void*)p;
#pragma unroll
    for (int c = 0; c < 8; c++) f[c] = b2f(x[c]);
}
DI void ld8(const float* p, float* f) {
    float4 a = *(const float4*)p, b = *(const float4*)(p + 4);
    f[0]=a.x; f[1]=a.y; f[2]=a.z; f[3]=a.w; f[4]=b.x; f[5]=b.y; f[6]=b.z; f[7]=b.w;
}

typedef const __attribute__((address_space(1))) void* gp_t;
typedef __attribute__((address_space(3))) void* lp_t;
DI void gload_lds16(const void* g, void* l) {
    __builtin_amdgcn_global_load_lds((gp_t)g, (lp_t)l, 16, 0, 0);
}

// ---------------- diagnostic ----------------
__global__ void diag_k(float* out, float v) { out[0] = v; }

// ---------------- fp32 -> bf16 weight conversion (8/thread) ----------------
__global__ void f2bf_k(const float* __restrict__ in, bf16* __restrict__ out, int n) {
    int i = (blockIdx.x * 256 + threadIdx.x) * 8;
    if (i >= n) return;
    float f[8];
    ld8(in + i, f);
    s16x8 o;
#pragma unroll
    for (int c = 0; c < 8; c++) o[c] = f2b(f[c]);
    *(s16x8*)(void*)(out + i) = o;
}

// ---------------- depthwise 3x3 conv v4 ----------------
// CPL channels per lane (group = 64*CPL channels). Stores are 64 lanes x
// 4B contiguous = 256B (full L2 line, no cross-XCD half-line write amp).
// LDS pad 33 (+ odd/even row interleave for CPL=2) -> 2-way max (free).
DI void tap10(const float* r, float w0, float w1, float w2, float* acc) {
#pragma unroll
    for (int i = 0; i < 8; i++)
        acc[i] += w0 * r[i] + w1 * r[i + 1] + w2 * r[i + 2];
}

template <typename TI, typename TO, bool RESID, int CPL>
__global__ __launch_bounds__(256) void conv4_k(
    const TI* in, long rs, long coff,
    const float* __restrict__ w, const float* __restrict__ bias,
    TO* out, long ors, int gshift)
{
    constexpr int CH = 64 * CPL;          // channels per group
    constexpr int ECNT = CH / 8;          // staged elems per thread
    __shared__ float buf[2][CH][33];
    const int t = threadIdx.x;
    const int band = blockIdx.x & 3;
    const int cg = (blockIdx.x >> 2) & ((1 << gshift) - 1);
    const int img = blockIdx.x >> (2 + gshift);
    const int y0 = band * 8;

    const int spx = t >> 3;               // pixel 0..31
    const int sce = (t & 7) * ECNT;       // first staged channel
    const TI* gsrc = in + ((long)img << 10) * rs + coff + (long)cg * CH + sce;

    const int c = t & 63;                 // lane channel(-pair) index
    const int xb = (t >> 6) * 8;          // x-octet base

    float wv9[9][CPL], bw[CPL];
#pragma unroll
    for (int p = 0; p < CPL; p++) {
        const int gch = cg * CH + c * CPL + p;
#pragma unroll
        for (int j = 0; j < 9; j++) wv9[j][p] = w[gch * 9 + j];
        bw[p] = bias[gch];
    }

    auto stage = [&](int row) {
        float f[ECNT];
        ld8(gsrc + (long)(row * 32 + spx) * rs, f);
        if constexpr (ECNT == 16) ld8(gsrc + (long)(row * 32 + spx) * rs + 8, f + 8);
        float* d = &buf[row & 1][0][0];
#pragma unroll
        for (int k = 0; k < ECNT; k++) {
            const int ch = sce + k;
            const int rr = (CPL == 2) ? ((ch & 1) * 64 + (ch >> 1)) : ch;
            d[rr * 33 + spx] = f[k];
        }
    };
    auto slice = [&](int row, float r[CPL][10]) {
#pragma unroll
        for (int p = 0; p < CPL; p++) {
            const float* s = &buf[row & 1][c + p * 64][0];
            r[p][0] = (xb == 0) ? 0.f : s[xb - 1];
#pragma unroll
            for (int i = 0; i < 8; i++) r[p][1 + i] = s[xb + i];
            r[p][9] = (xb + 8 >= 32) ? 0.f : s[xb + 8];
        }
    };
    auto zero = [&](float r[CPL][10]) {
#pragma unroll
        for (int p = 0; p < CPL; p++)
#pragma unroll
            for (int i = 0; i < 10; i++) r[p][i] = 0.f;
    };

    float r0[CPL][10], r1[CPL][10], r2[CPL][10];
    if (y0 > 0) stage(y0 - 1);
    __syncthreads();
    if (y0 > 0) slice(y0 - 1, r0); else zero(r0);
    stage(y0);
    __syncthreads();
    slice(y0, r1);

    for (int y = y0; y < y0 + 8; ++y) {
        const int yn = y + 1;
        if (yn <= 31) stage(yn);
        __syncthreads();
        if (yn <= 31) slice(yn, r2); else zero(r2);
        float acc[CPL][8];
#pragma unroll
        for (int p = 0; p < CPL; p++) {
#pragma unroll
            for (int i = 0; i < 8; i++) acc[p][i] = bw[p];
            tap10(r0[p], wv9[0][p], wv9[1][p], wv9[2][p], acc[p]);
            tap10(r1[p], wv9[3][p], wv9[4][p], wv9[5][p], acc[p]);
            tap10(r2[p], wv9[6][p], wv9[7][p], wv9[8][p], acc[p]);
            if (RESID) {
#pragma unroll
                for (int i = 0; i < 8; i++) acc[p][i] += r1[p][i + 1];
            }
        }
        TO* o = out + ((long)(img * 1024 + y * 32 + xb)) * ors + (long)cg * CH + c * CPL;
#pragma unroll
        for (int i = 0; i < 8; i++) {
            if constexpr (CPL == 2 && sizeof(TO) == 2) {
                const unsigned u = (unsigned)(unsigned short)f2b(acc[0][i]) |
                                   ((unsigned)(unsigned short)f2b(acc[1][i]) << 16);
                *(unsigned*)(void*)(o + (long)i * ors) = u;
            } else {
                o[(long)i * ors] = (TO)acc[0][i];
            }
        }
#pragma unroll
        for (int p = 0; p < CPL; p++)
#pragma unroll
            for (int i = 0; i < 10; i++) { r0[p][i] = r1[p][i]; r1[p][i] = r2[p][i]; }
    }
}

// ---------------- LayerNorm over C=512, fp32 in -> bf16 out ----------------
__global__ __launch_bounds__(64) void ln_k(const float* __restrict__ x,
                                           const float* __restrict__ w,
                                           const float* __restrict__ bp,
                                           bf16* __restrict__ out)
{
    const size_t row = blockIdx.x;
    const float* xr = x + row * 512;
    const int t = threadIdx.x;
    alignas(16) float v[8];
    *(float4*)&v[0] = *(const float4*)(xr + t * 8);
    *(float4*)&v[4] = *(const float4*)(xr + t * 8 + 4);
    float s = 0.f;
#pragma unroll
    for (int j = 0; j < 8; j++) s += v[j];
#pragma unroll
    for (int mm = 32; mm; mm >>= 1) s += __shfl_xor(s, mm);
    const float mu = s * (1.f / 512.f);
    float q = 0.f;
#pragma unroll
    for (int j = 0; j < 8; j++) { v[j] -= mu; q += v[j] * v[j]; }
#pragma unroll
    for (int mm = 32; mm; mm >>= 1) q += __shfl_xor(q, mm);
    const float rstd = rsqrtf(q * (1.f / 512.f) + 1e-6f);
    alignas(16) float wv[8], bv[8];
    *(float4*)&wv[0] = *(const float4*)(w + t * 8);
    *(float4*)&wv[4] = *(const float4*)(w + t * 8 + 4);
    *(float4*)&bv[0] = *(const float4*)(bp + t * 8);
    *(float4*)&bv[4] = *(const float4*)(bp + t * 8 + 4);
    alignas(16) bf16 o[8];
#pragma unroll
    for (int j = 0; j < 8; j++) o[j] = __float2bfloat16(v[j] * rstd * wv[j] + bv[j]);
    *(uint4*)(out + row * 512 + t * 8) = *(const uint4*)o;
}

// ---------------- bf16 MFMA GEMM: C[M,N] = A[M,K] * Bw[N,K]^T ----------------
// 3-buffer LDS pipeline, counted vmcnt, one raw s_barrier per K-step.
// XOR swizzle on global source + ds_read side; LDS dest linear.
template <int EPI, int BN>
__global__ __launch_bounds__(256) void gemm_k(
    const bf16* __restrict__ A, const bf16* __restrict__ Bw,
    const float* __restrict__ bias, const float* resid,
    bf16* __restrict__ outb, float* outf,
    int M, int Nn, int K)
{
    constexpr int WC = (BN == 128) ? 2 : 1;
    constexpr int WR = 4 / WC;
    constexpr int MI = 128 / (16 * WR);
    constexpr int NJ = BN / (16 * WC);
    __shared__ __align__(16) short As[3][128 * 32];
    __shared__ __align__(16) short Bs[3][BN * 32];
    const int t = threadIdx.x;
    const int m0 = blockIdx.x * 128;
    const int n0 = blockIdx.y * BN;
    const int lane = t & 63;
    const int wv = t >> 6;
    const int wr = (WC == 2) ? (wv >> 1) : wv;
    const int wc = (WC == 2) ? (wv & 1) : 0;
    const int lr = lane & 15, lg = lane >> 4;

    f32x4 acc[MI][NJ] = {};

    const int sk = 8 * ((lane & 3) ^ ((lane >> 3) & 3));
    const int arow = wv * 32 + (lane >> 2);
    const bf16* Ag0 = A + (size_t)(m0 + arow) * K + sk;
    const bf16* Ag1 = Ag0 + (size_t)16 * K;
    const int brow = (BN == 128) ? arow : (wv * 16 + (lane >> 2));
    const bf16* Bg0 = Bw + (size_t)(n0 + brow) * K + sk;
    const bf16* Bg1 = Bg0 + (size_t)16 * K;

    const int rsw = (lr >> 1) & 3;

    auto STAGE = [&](int buf, int k0) {
        gload_lds16(Ag0 + k0, (char*)&As[buf][0] + wv * 2048);
        gload_lds16(Ag1 + k0, (char*)&As[buf][0] + wv * 2048 + 1024);
        if constexpr (BN == 128) {
            gload_lds16(Bg0 + k0, (char*)&Bs[buf][0] + wv * 2048);
            gload_lds16(Bg1 + k0, (char*)&Bs[buf][0] + wv * 2048 + 1024);
        } else {
            gload_lds16(Bg0 + k0, (char*)&Bs[buf][0] + wv * 1024);
        }
    };

    auto COMPUTE = [&](int buf) {
        s16x8 aF[MI], bF[NJ];
#pragma unroll
        for (int i = 0; i < MI; i++) {
            const int R = wr * (128 / WR) + i * 16 + lr;
            aF[i] = *(const s16x8*)(&As[buf][0] + R * 32 + ((lg ^ rsw) << 3));
        }
#pragma unroll
        for (int j = 0; j < NJ; j++) {
            const int R = wc * 64 + j * 16 + lr;
            bF[j] = *(const s16x8*)(&Bs[buf][0] + R * 32 + ((lg ^ rsw) << 3));
        }
#pragma unroll
        for (int i = 0; i < MI; i++)
#pragma unroll
            for (int j = 0; j < NJ; j++)
                acc[i][j] = __builtin_amdgcn_mfma_f32_16x16x32_bf16(aF[i], bF[j], acc[i][j], 0, 0, 0);
    };

    const int KT = K / 32;
    STAGE(0, 0);
    STAGE(1, 32);
    int cur = 0;
    for (int kt = 0; kt < KT - 1; ++kt) {
        if constexpr (BN == 128) asm volatile("s_waitcnt vmcnt(4)" ::: "memory");
        else                     asm volatile("s_waitcnt vmcnt(3)" ::: "memory");
        __builtin_amdgcn_s_barrier();
        if (kt + 2 < KT) {
            int s = cur + 2; if (s >= 3) s -= 3;
            STAGE(s, (kt + 2) * 32);
        }
        COMPUTE(cur);
        if (++cur == 3) cur = 0;
    }
    asm volatile("s_waitcnt vmcnt(0)" ::: "memory");
    __builtin_amdgcn_s_barrier();
    COMPUTE(cur);

#pragma unroll
    for (int i = 0; i < MI; i++) {
#pragma unroll
        for (int j = 0; j < NJ; j++) {
            const int col = n0 + wc * 64 + j * 16 + lr;
            const float bcol = (EPI > 0) ? bias[col] : 0.f;
#pragma unroll
            for (int r = 0; r < 4; r++) {
                const int row = m0 + wr * (128 / WR) + i * 16 + lg * 4 + r;
                float v = acc[i][j][r] + bcol;
                const size_t idx = (size_t)row * Nn + col;
                if (EPI == 0) outb[idx] = __float2bfloat16(v);
                else if (EPI == 1) outb[idx] = __float2bfloat16(gelu_f(v));
                else outf[idx] = v + resid[idx];
            }
        }
    }
}

// ---------------- ktv partials: no max-subtraction softmax -------------------
__global__ __launch_bounds__(256) void ktv_part_k(const bf16* __restrict__ qkv,
                                                  float* __restrict__ ktvp,
                                                  float* __restrict__ csp)
{
    const int b = blockIdx.x >> 5;
    const int hh = (blockIdx.x >> 2) & 7;
    const int sp = blockIdx.x & 3;
    const bf16* kb = qkv + (size_t)b * 1024 * 1536 + 512 + hh * 64;
    const bf16* vb = kb + 512;
    __shared__ __align__(16) bf16 Ks[16 * 64];
    __shared__ __align__(16) bf16 Vs[16 * 64];
    const int t = threadIdx.x;
    const int kk = t & 63, vg = t >> 6;
    float acc[16] = {};
    float psum = 0.f;
    const int sr = t >> 4, sc = (t & 15) * 4;
    for (int n0 = sp * 256; n0 < sp * 256 + 256; n0 += 16) {
        __syncthreads();
        *(s16x4*)(void*)(Ks + sr * 64 + sc) = *(const s16x4*)(const void*)(kb + (size_t)(n0 + sr) * 1536 + sc);
        *(s16x4*)(void*)(Vs + sr * 64 + sc) = *(const s16x4*)(const void*)(vb + (size_t)(n0 + sr) * 1536 + sc);
        __syncthreads();
#pragma unroll
        for (int i = 0; i < 16; i++) {
            const float p = __expf(b2f(*(const short*)(const void*)(Ks + i * 64 + kk)));
            psum += p;
            float vv[16];
            ld8(Vs + i * 64 + vg * 16, vv);
            ld8(Vs + i * 64 + vg * 16 + 8, vv + 8);
#pragma unroll
            for (int j = 0; j < 16; j++) acc[j] += p * vv[j];
        }
    }
    const int bh4 = (b * 8 + hh) * 4 + sp;
    float* o = ktvp + (size_t)bh4 * 4096 + kk * 64 + vg * 16;
#pragma unroll
    for (int j = 0; j < 16; j++) o[j] = acc[j];
    if (vg == 0) csp[bh4 * 64 + kk] = psum;
}

// ---------------- ktv reduce ----------
__global__ __launch_bounds__(256) void ktv_red_k(const float* __restrict__ ktvp,
                                                 const float* __restrict__ csp,
                                                 float* __restrict__ ktv)
{
    const int bh = blockIdx.x;
    const int t = threadIdx.x;
#pragma unroll
    for (int i = 0; i < 16; i++) {
        const int e = t + 256 * i;
        const int kk = e >> 6;
        float cs = 0.f, v = 0.f;
#pragma unroll
        for (int sp = 0; sp < 4; sp++) {
            cs += csp[(bh * 4 + sp) * 64 + kk];
            v += ktvp[(size_t)(bh * 4 + sp) * 4096 + e];
        }
        ktv[(size_t)bh * 4096 + e] = v * (0.125f / cs);
    }
}

// ---------------- xs += q @ ktv_scaled + q * vconv  (in place) --------------
__global__ __launch_bounds__(256) void attnout_k(
    float* xs, const bf16* __restrict__ qkv,
    const float* __restrict__ ktv, const bf16* __restrict__ vc)
{
    const int nc = blockIdx.x & 31, hh = (blockIdx.x >> 5) & 7, b = blockIdx.x >> 8;
    __shared__ __align__(16) float kt[64 * 64];
    __shared__ __align__(16) bf16 qs[32 * 64];
    const int t = threadIdx.x;
    const float4* ksrc = (const float4*)(ktv + (size_t)(b * 8 + hh) * 4096);
    for (int u = t; u < 1024; u += 256) ((float4*)kt)[u] = ksrc[u];
    const int n0 = nc * 32;
    {
        const int r = t >> 3, cc = (t & 7) * 8;
        *(uint4*)(qs + r * 64 + cc) =
            *(const uint4*)(qkv + ((size_t)b * 1024 + n0 + r) * 1536 + hh * 64 + cc);
    }
    __syncthreads();
    const int dv = t & 63, rb = (t >> 6) * 8;
    for (int r = rb; r < rb + 8; r++) {
        float fa = 0.f;
#pragma unroll
        for (int kk = 0; kk < 64; kk++)
            fa += b2f(*(const short*)(const void*)(qs + r * 64 + kk)) * kt[kk * 64 + dv];
        const size_t idx = ((size_t)b * 1024 + n0 + r) * 512 + hh * 64 + dv;
        const float qv = b2f(*(const short*)(const void*)(qs + r * 64 + dv));
        xs[idx] = xs[idx] + fa + qv * __bfloat162float(vc[idx]);
    }
}

// ---------------- workspace layout (bytes) ----------------------------------
static constexpr int    BC       = 8;
static constexpr size_t OFF_WQ   = 0;
static constexpr size_t OFF_W1   = 1572864;
static constexpr size_t OFF_W2   = 3670016;
static constexpr size_t OFF_CUR  = 5767168;
static constexpr size_t OFF_QKV  = 14155776;
static constexpr size_t OFF_KTVP = 39321600;
static constexpr size_t OFF_CSP  = 43515904;
static constexpr size_t OFF_KTV  = 43581440;
static constexpr size_t OFF_VC   = 44630016;   // ends 53018624
static constexpr size_t OFF_HG   = 14155776;   // over dead qkv region
static constexpr size_t OFF_H2S  = 47710208;   // small mode: over dead vc tail (32MB)
static constexpr size_t WS_NEED  = 81264640;   // small mode ~77.5MB
static constexpr size_t OFF_H2B  = 53018624;   // big mode: 64MB pair buffer
static constexpr size_t WS_BIG   = 120127488;  // ~114.6MB

extern "C" void kernel_launch(void* const* d_in, const int* in_sizes, int n_in,
                              void* d_out, int out_size, void* d_ws, size_t ws_size,
                              hipStream_t stream)
{
    const float* x     = (const float*)d_in[0];
    const float* cpe_w = (const float*)d_in[1];
    const float* cpe_b = (const float*)d_in[2];
    const float* ln1_w = (const float*)d_in[3];
    const float* ln1_b = (const float*)d_in[4];
    const float* qkv_w = (const float*)d_in[5];
    const float* crpe_w= (const float*)d_in[6];
    const float* crpe_b= (const float*)d_in[7];
    const float* ln2_w = (const float*)d_in[8];
    const float* ln2_b = (const float*)d_in[9];
    const float* fc1_w = (const float*)d_in[10];
    const float* fc1_b = (const float*)d_in[11];
    const float* dw_w  = (const float*)d_in[12];
    const float* dw_b  = (const float*)d_in[13];
    const float* fc2_w = (const float*)d_in[14];
    const float* fc2_b = (const float*)d_in[15];
    float* spine = (float*)d_out;
    char* ws = (char*)d_ws;

    if (ws_size < WS_NEED) {
        diag_k<<<1, 1, 0, stream>>>(spine, (float)ws_size);
        return;
    }
    const bool big = ws_size >= WS_BIG;

    bf16*  wq   = (bf16*)(ws + OFF_WQ);
    bf16*  w1   = (bf16*)(ws + OFF_W1);
    bf16*  w2   = (bf16*)(ws + OFF_W2);
    bf16*  cur  = (bf16*)(ws + OFF_CUR);
    bf16*  qkv  = (bf16*)(ws + OFF_QKV);
    float* ktvp = (float*)(ws + OFF_KTVP);
    float* csp  = (float*)(ws + OFF_CSP);
    float* ktv  = (float*)(ws + OFF_KTV);
    bf16*  vc   = (bf16*)(ws + OFF_VC);
    bf16*  hg   = (bf16*)(ws + OFF_HG);
    bf16*  h2   = (bf16*)(ws + (big ? OFF_H2B : OFF_H2S));

    // weights -> bf16
    f2bf_k<<<(1536 * 512 / 8 + 255) / 256, 256, 0, stream>>>(qkv_w, wq, 1536 * 512);
    f2bf_k<<<(2048 * 512 / 8 + 255) / 256, 256, 0, stream>>>(fc1_w, w1, 2048 * 512);
    f2bf_k<<<(2048 * 512 / 8 + 255) / 256, 256, 0, stream>>>(fc2_w, w2, 2048 * 512);

    // CPE (full batch, fp32, 64-ch groups): spine = x + dwconv(x) + cpe_b
    conv4_k<float, float, true, 1><<<32 * 8 * 4, 256, 0, stream>>>(x, 512, 0, cpe_w, cpe_b, spine, 512, 3);

    const int Mc = BC * 1024;  // 8192 rows per chunk
    for (int pair = 0; pair < 2; pair++) {
        for (int ci = 0; ci < 2; ci++) {
            const int c = pair * 2 + ci;
            float* xs = spine + (size_t)c * Mc * 512;
            bf16* h2c = big ? (h2 + (size_t)ci * Mc * 2048) : h2;
            ln_k<<<Mc, 64, 0, stream>>>(xs, ln1_w, ln1_b, cur);
            gemm_k<0, 128><<<dim3(Mc / 128, 12), 256, 0, stream>>>(cur, wq, nullptr, nullptr, qkv, nullptr, Mc, 1536, 512);
            ktv_part_k<<<BC * 8 * 4, 256, 0, stream>>>(qkv, ktvp, csp);
            ktv_red_k<<<BC * 8, 256, 0, stream>>>(ktvp, csp, ktv);
            // crpe conv on v (bf16, 128-ch groups: 4 groups)
            conv4_k<bf16, bf16, false, 2><<<BC * 4 * 4, 256, 0, stream>>>(qkv, 1536, 1024, crpe_w, crpe_b, vc, 512, 2);
            attnout_k<<<BC * 8 * 32, 256, 0, stream>>>(xs, qkv, ktv, vc);
            ln_k<<<Mc, 64, 0, stream>>>(xs, ln2_w, ln2_b, cur);
            gemm_k<1, 128><<<dim3(Mc / 128, 16), 256, 0, stream>>>(cur, w1, fc1_b, nullptr, hg, nullptr, Mc, 2048, 512);
            // hidden dwconv residual (bf16, 128-ch groups: 16 groups)
            conv4_k<bf16, bf16, true, 2><<<BC * 16 * 4, 256, 0, stream>>>(hg, 2048, 0, dw_w, dw_b, h2c, 2048, 4);
            if (!big) {
                gemm_k<2, 64><<<dim3(Mc / 128, 8), 256, 0, stream>>>(h2, w2, fc2_b, xs, nullptr, xs, Mc, 512, 2048);
            }
        }
        if (big) {
            float* xsp = spine + (size_t)pair * 2 * Mc * 512;
            gemm_k<2, 128><<<dim3(2 * Mc / 128, 4), 256, 0, stream>>>(h2, w2, fc2_b, xsp, nullptr, xsp, 2 * Mc, 512, 2048);
        }
    }
}